// Round 3
// baseline (1182.930 us; speedup 1.0000x reference)
//
#include <hip/hip_runtime.h>
#include <math.h>

// ---- problem constants ----
#define B   64
#define L   64
#define C   16
#define CHD 64
#define EMB 300
#define D   450       // EMB + 3*50
#define NT  (B*L)     // 4096 tokens per branch
#define NBH 128       // 2 branches * 64 batch

// ---------------- wave helpers (wave64) ----------------
__device__ inline float wave_sum(float v) {
#pragma unroll
    for (int o = 32; o; o >>= 1) v += __shfl_xor(v, o, 64);
    return v;
}
__device__ inline float wave_max(float v) {
#pragma unroll
    for (int o = 32; o; o >>= 1) v = fmaxf(v, __shfl_xor(v, o, 64));
    return v;
}

// ---------------- kernel 0: word embedding copy ----------------
__global__ __launch_bounds__(256) void wordcopy_kernel(
    const int* __restrict__ q1, const int* __restrict__ q2,
    const float* __restrict__ word_emb, float* __restrict__ xout)
{
    const int tid = threadIdx.x;
#pragma unroll
    for (int t = 0; t < 4; ++t) {
        const int tok    = blockIdx.x * 4 + t;
        const int branch = tok >> 12;
        const int tokl   = tok & (NT - 1);
        const int w      = (branch ? q2 : q1)[tokl];
        const float* src = word_emb + (size_t)w * EMB;
        float*       dst = xout + (size_t)tok * D;
        for (int d = tid; d < EMB; d += 256) dst[d] = src[d];
    }
}

// ---------------- kernel 1: char conv, LDS weights ----------------
template <int K, int OFF>
__global__ __launch_bounds__(256) void conv_kernel(
    const int* __restrict__ q1c, const int* __restrict__ q2c,
    const float* __restrict__ char_emb,
    const float* __restrict__ wconv, const float* __restrict__ bias,
    float* __restrict__ xout)
{
    const int P = C - K + 1;
    const int tid  = threadIdx.x;
    const int w    = tid >> 6;
    const int lane = tid & 63;
    const int f    = (lane < 50) ? lane : 49;

    __shared__ float2 wl2[32 * K * 50];
    __shared__ float  es[4][16 * 64];

    const int N2 = 32 * K * 50;
    for (int idx = tid; idx < N2; idx += 256) {
        int fr   = idx % 50;
        int rest = idx / 50;
        int k    = rest % K;
        int d2   = rest / K;
        const float* wp = wconv + (size_t)fr * CHD * K;
        wl2[idx] = make_float2(wp[d2 * K + k], wp[(d2 + 32) * K + k]);
    }
    const float bf = (lane < 50) ? bias[f] : 0.f;

#pragma unroll 1
    for (int t = 0; t < 8; ++t) {
        __syncthreads();
        const int tok    = blockIdx.x * 32 + w * 8 + t;
        const int branch = tok >> 12;
        const int tokl   = tok & (NT - 1);
        const int* qcrow = (branch ? q2c : q1c) + (size_t)tokl * C;

        int chv = (lane < 16) ? qcrow[lane] : 0;
        const int d2w = lane & 31, hw_ = lane >> 5;
#pragma unroll
        for (int r = 0; r < C; ++r) {
            int c = __shfl(chv, r, 64);
            es[w][r * 64 + d2w * 2 + hw_] = char_emb[(size_t)c * CHD + lane];
        }
        __syncthreads();

        const float2* es2 = (const float2*)es[w];
        float2 acc2[P];
#pragma unroll
        for (int p = 0; p < P; ++p) acc2[p] = make_float2(0.f, 0.f);

#pragma unroll 1
        for (int d2 = 0; d2 < 32; ++d2) {
            float2 e2[C];
#pragma unroll
            for (int r = 0; r < C; ++r) e2[r] = es2[r * 32 + d2];
#pragma unroll
            for (int k = 0; k < K; ++k) {
                float2 wv = wl2[(d2 * K + k) * 50 + f];
#pragma unroll
                for (int p = 0; p < P; ++p) {
                    acc2[p].x = fmaf(e2[p + k].x, wv.x, acc2[p].x);
                    acc2[p].y = fmaf(e2[p + k].y, wv.y, acc2[p].y);
                }
            }
        }
        float m = acc2[0].x + acc2[0].y;
#pragma unroll
        for (int p = 1; p < P; ++p) m = fmaxf(m, acc2[p].x + acc2[p].y);
        float r = fmaxf(0.f, m + bf);
        if (lane < 50)
            xout[(size_t)tok * D + EMB + OFF + lane] = r;
    }
}

// ---------------- kernel 2: highway (64x64 tile, BK=32, grid 8x128) ----------------
#define HBK 32
#define HPAD 68

__global__ __launch_bounds__(256) void highway_kernel(
    const float* __restrict__ x, const float* __restrict__ W,
    const float* __restrict__ bvec, float* __restrict__ out)
{
    const int tid = threadIdx.x;
    const int tx = tid & 15, ty = tid >> 4;
    const int n0 = blockIdx.x * 64;
    const int m0 = blockIdx.y * 64;
    const int m4 = ty * 4, n4 = tx * 4;

    __shared__ float As[HBK][HPAD];
    __shared__ float Bs[HBK][HPAD];

    float acc[4][4] = {};
#pragma unroll 1
    for (int k0 = 0; k0 < D; k0 += HBK) {
        __syncthreads();
#pragma unroll
        for (int it = 0; it < 8; ++it) {
            int idx = tid + it * 256;
            int k = idx & 31, r = idx >> 5;
            int gk = k0 + k;
            As[k][r] = (gk < D) ? x[(size_t)(m0 + r) * D + gk] : 0.f;
            int gn = n0 + r;
            Bs[k][r] = (gk < D && gn < D) ? W[(size_t)gn * D + gk] : 0.f;
        }
        __syncthreads();
#pragma unroll
        for (int kk = 0; kk < HBK; ++kk) {
            float4 a = *(const float4*)&As[kk][m4];
            float4 bq = *(const float4*)&Bs[kk][n4];
            const float av[4] = {a.x, a.y, a.z, a.w};
            const float bv[4] = {bq.x, bq.y, bq.z, bq.w};
#pragma unroll
            for (int i = 0; i < 4; ++i)
#pragma unroll
                for (int j = 0; j < 4; ++j) acc[i][j] = fmaf(av[i], bv[j], acc[i][j]);
        }
    }
#pragma unroll
    for (int i = 0; i < 4; ++i) {
        const int m = m0 + m4 + i;
#pragma unroll
        for (int j = 0; j < 4; ++j) {
            const int n = n0 + n4 + j;
            if (n < D) {
                float y  = acc[i][j] + bvec[n];
                float g  = 1.f / (1.f + __expf(-y));
                float xo = x[(size_t)m * D + n];
                out[(size_t)m * D + n] = g * fmaxf(y, 0.f) + (1.f - g) * xo;
            }
        }
    }
}

// ---------------- kernel 3a: s1[i] = x_i.w1, s2[j] = x_j.w2 ----------------
// grid (NBH, 2), block 64
__global__ __launch_bounds__(64) void s12_kernel(
    const float* __restrict__ x, const float* __restrict__ attn_w,
    int layer, float* __restrict__ s12)
{
    const int bh    = blockIdx.x;
    const int which = blockIdx.y;
    const int lane  = threadIdx.x;
    const float* wv = attn_w + (size_t)layer * 3 * D + (size_t)which * D;
    const float* xb = x + (size_t)bh * L * D;

    float wr[8];
#pragma unroll
    for (int t = 0; t < 8; ++t) {
        int k = lane + t * 64;
        wr[t] = (k < D) ? wv[k] : 0.f;
    }
#pragma unroll 1
    for (int r = 0; r < L; ++r) {
        const float* xr = xb + (size_t)r * D;
        float p = 0.f;
#pragma unroll
        for (int t = 0; t < 8; ++t) {
            int k = lane + t * 64;
            if (k < D) p = fmaf(xr[k], wr[t], p);
        }
        p = wave_sum(p);
        if (lane == 0) s12[(size_t)bh * 128 + which * 64 + r] = p;
    }
}

// ---------------- kernel 3b: scores + softmax -> A ----------------
// grid (4 i-tiles, NBH), block 256; S[i][j] = sum_k X[i][k]*X[j][k]*w3[k] + s1 + s2 + b
#define APAD 68

__global__ __launch_bounds__(256) void attn_score_kernel(
    const float* __restrict__ x,
    const int* __restrict__ q1_len, const int* __restrict__ q2_len,
    const float* __restrict__ attn_w, const float* __restrict__ attn_b,
    const float* __restrict__ s12, int layer, float* __restrict__ A_g)
{
    const int it = blockIdx.x, bh = blockIdx.y;
    const int i0 = it * 16;
    const int branch = bh >> 6, b = bh & 63;
    const int tid = threadIdx.x;
    const int tj = tid & 15, ti = tid >> 4;   // ti: i-row 0..15, tj: j-quad

    const float* xb  = x + (size_t)bh * L * D;
    const float* w3g = attn_w + (size_t)layer * 3 * D + 2 * D;

    __shared__ float As[32][17];
    __shared__ float Bs[32][APAD];
    __shared__ float Ssh[16][65];

    float acc[4] = {};
#pragma unroll 1
    for (int k0 = 0; k0 < D; k0 += 32) {
        __syncthreads();
        // stage Xi (16x32)
#pragma unroll
        for (int u = 0; u < 2; ++u) {
            int idx = tid + u * 256;
            int k = idx & 31, i = idx >> 5;
            int gk = k0 + k;
            As[k][i] = (gk < D) ? xb[(size_t)(i0 + i) * D + gk] : 0.f;
        }
        // stage Xj*w3 (64x32)
#pragma unroll
        for (int u = 0; u < 8; ++u) {
            int idx = tid + u * 256;
            int k = idx & 31, j = idx >> 5;
            int gk = k0 + k;
            Bs[k][j] = (gk < D) ? xb[(size_t)j * D + gk] * w3g[gk] : 0.f;
        }
        __syncthreads();
#pragma unroll
        for (int kk = 0; kk < 32; ++kk) {
            float a = As[kk][ti];
            float4 bq = *(const float4*)&Bs[kk][tj * 4];
            acc[0] = fmaf(a, bq.x, acc[0]);
            acc[1] = fmaf(a, bq.y, acc[1]);
            acc[2] = fmaf(a, bq.z, acc[2]);
            acc[3] = fmaf(a, bq.w, acc[3]);
        }
    }
#pragma unroll
    for (int q = 0; q < 4; ++q) Ssh[ti][tj * 4 + q] = acc[q];
    __syncthreads();

    const int   len  = (branch ? q2_len : q1_len)[b];
    const float bias = attn_b[layer];
    const float* s1p = s12 + (size_t)bh * 128;
    const float* s2p = s1p + 64;

    const int j  = tid & 63;
    const int rq = tid >> 6;
    const float s2v = s2p[j];
#pragma unroll
    for (int rr = 0; rr < 4; ++rr) {
        const int r = rq * 4 + rr;
        float s = Ssh[r][j] + s1p[i0 + r] + s2v + bias;
        if (j >= len) s = -1e-9f;            // reference's (buggy) mask value
        const float mx = wave_max(s);
        const float ev = __expf(s - mx);
        const float sm = wave_sum(ev);
        A_g[(size_t)bh * (L * L) + (size_t)(i0 + r) * L + j] = ev / sm;
    }
}

// ---------------- kernel 3c: out = A @ X (+ residual) ----------------
// grid (8 d-tiles, NBH), block 256
__global__ __launch_bounds__(256) void attn_av_kernel(
    const float* __restrict__ x, const float* __restrict__ A_g,
    int add_resid, float* __restrict__ out)
{
    const int dt = blockIdx.x, bh = blockIdx.y;
    const int d0 = dt * 64;
    const int tid = threadIdx.x;
    const int td = tid & 15, ti = tid >> 4;
    const int d4 = td * 4, i4 = ti * 4;

    const float* xb = x + (size_t)bh * L * D;
    const float* Ab = A_g + (size_t)bh * (L * L);

    __shared__ float Ash[L][APAD];   // [k=j][i]
    __shared__ float Xc[L][APAD];    // [k=j][d]

#pragma unroll
    for (int u = 0; u < 16; ++u) {
        int idx = tid + u * 256;
        int j = idx & 63, i = idx >> 6;
        i += (u & 3) * 0;  // idx>>6 spans 0..15 over u? no: compute directly
    }
    // stage A transposed: 4096 elems
    for (int idx = tid; idx < L * L; idx += 256) {
        int j = idx & 63, i = idx >> 6;
        Ash[j][i] = Ab[(size_t)i * L + j];
    }
    // stage X chunk: 64 x 64
    for (int idx = tid; idx < L * 64; idx += 256) {
        int d = idx & 63, j = idx >> 6;
        int gd = d0 + d;
        Xc[j][d] = (gd < D) ? xb[(size_t)j * D + gd] : 0.f;
    }
    __syncthreads();

    float acc[4][4] = {};
#pragma unroll
    for (int k = 0; k < L; ++k) {
        float4 av = *(const float4*)&Ash[k][i4];
        float4 xv = *(const float4*)&Xc[k][d4];
        const float a[4] = {av.x, av.y, av.z, av.w};
        const float xr[4] = {xv.x, xv.y, xv.z, xv.w};
#pragma unroll
        for (int i = 0; i < 4; ++i)
#pragma unroll
            for (int d = 0; d < 4; ++d) acc[i][d] = fmaf(a[i], xr[d], acc[i][d]);
    }

    float* ob = out + (size_t)bh * L * D;
#pragma unroll
    for (int i = 0; i < 4; ++i) {
        const int gi = i4 + i;
#pragma unroll
        for (int d = 0; d < 4; ++d) {
            const int gd = d0 + d4 + d;
            if (gd < D) {
                float v = acc[i][d];
                if (add_resid) v += Xc[gi][d4 + d];
                ob[(size_t)gi * D + gd] = v;
            }
        }
    }
}

// ---------------- launch ----------------
extern "C" void kernel_launch(void* const* d_in, const int* in_sizes, int n_in,
                              void* d_out, int out_size, void* d_ws, size_t ws_size,
                              hipStream_t stream) {
    const int*   q1       = (const int*)  d_in[0];
    const int*   q2       = (const int*)  d_in[1];
    const int*   q1_len   = (const int*)  d_in[2];
    const int*   q2_len   = (const int*)  d_in[3];
    const int*   q1c      = (const int*)  d_in[4];
    const int*   q2c      = (const int*)  d_in[5];
    const float* word_emb = (const float*)d_in[6];
    const float* char_emb = (const float*)d_in[7];
    const float* w3       = (const float*)d_in[8];
    const float* b3       = (const float*)d_in[9];
    const float* w4       = (const float*)d_in[10];
    const float* b4       = (const float*)d_in[11];
    const float* w5       = (const float*)d_in[12];
    const float* b5       = (const float*)d_in[13];
    const float* hw_w     = (const float*)d_in[14];
    const float* hw_b     = (const float*)d_in[15];
    const float* attn_w   = (const float*)d_in[16];
    const float* attn_b   = (const float*)d_in[17];
    float* out = (float*)d_out;

    float* buf0  = (float*)d_ws;                       // 2*NT*D
    float* buf1  = buf0 + (size_t)2 * NT * D;          // 2*NT*D
    float* A_g   = buf1 + (size_t)2 * NT * D;          // NBH*L*L
    float* s12_g = A_g + (size_t)NBH * L * L;          // NBH*128

    // 1. embeddings + char conv -> buf0
    wordcopy_kernel<<<2 * NT / 4, 256, 0, stream>>>(q1, q2, word_emb, buf0);
    conv_kernel<3, 0>  <<<256, 256, 0, stream>>>(q1c, q2c, char_emb, w3, b3, buf0);
    conv_kernel<4, 50> <<<256, 256, 0, stream>>>(q1c, q2c, char_emb, w4, b4, buf0);
    conv_kernel<5, 100><<<256, 256, 0, stream>>>(q1c, q2c, char_emb, w5, b5, buf0);

    // 2. highway x2
    dim3 hgrid(8, (2 * NT) / 64);
    highway_kernel<<<hgrid, 256, 0, stream>>>(buf0, hw_w, hw_b, buf1);
    highway_kernel<<<hgrid, 256, 0, stream>>>(buf1, hw_w, hw_b, buf0);

    // 3. attn layer 0: x0 = buf0 -> x1 = buf1 (residual fused)
    s12_kernel<<<dim3(NBH, 2), 64, 0, stream>>>(buf0, attn_w, 0, s12_g);
    attn_score_kernel<<<dim3(4, NBH), 256, 0, stream>>>(
        buf0, q1_len, q2_len, attn_w, attn_b, s12_g, 0, A_g);
    attn_av_kernel<<<dim3(8, NBH), 256, 0, stream>>>(buf0, A_g, 1, buf1);

    // 4. attn layer 1: x1 = buf1 -> att -> d_out
    s12_kernel<<<dim3(NBH, 2), 64, 0, stream>>>(buf1, attn_w, 1, s12_g);
    attn_score_kernel<<<dim3(4, NBH), 256, 0, stream>>>(
        buf1, q1_len, q2_len, attn_w, attn_b, s12_g, 1, A_g);
    attn_av_kernel<<<dim3(8, NBH), 256, 0, stream>>>(buf1, A_g, 0, out);
}

// Round 4
// 990.909 us; speedup vs baseline: 1.1938x; 1.1938x over previous
//
#include <hip/hip_runtime.h>
#include <math.h>

// ---- problem constants ----
#define B   64
#define L   64
#define C   16
#define CHD 64
#define EMB 300
#define D   450       // EMB + 3*50
#define NT  (B*L)     // 4096 tokens per branch
#define NBH 128       // 2 branches * 64 batch

// ---------------- wave helpers (wave64) ----------------
__device__ inline float wave_sum(float v) {
#pragma unroll
    for (int o = 32; o; o >>= 1) v += __shfl_xor(v, o, 64);
    return v;
}
__device__ inline float wave_max(float v) {
#pragma unroll
    for (int o = 32; o; o >>= 1) v = fmaxf(v, __shfl_xor(v, o, 64));
    return v;
}

// ---------------- kernel 0: word embedding copy ----------------
__global__ __launch_bounds__(256) void wordcopy_kernel(
    const int* __restrict__ q1, const int* __restrict__ q2,
    const float* __restrict__ word_emb, float* __restrict__ xout)
{
    const int tid = threadIdx.x;
#pragma unroll
    for (int t = 0; t < 4; ++t) {
        const int tok    = blockIdx.x * 4 + t;
        const int branch = tok >> 12;
        const int tokl   = tok & (NT - 1);
        const int w      = (branch ? q2 : q1)[tokl];
        const float* src = word_emb + (size_t)w * EMB;
        float*       dst = xout + (size_t)tok * D;
        for (int d = tid; d < EMB; d += 256) dst[d] = src[d];
    }
}

// ---------------- kernel 1: char conv, LDS weights ----------------
template <int K, int OFF>
__global__ __launch_bounds__(256) void conv_kernel(
    const int* __restrict__ q1c, const int* __restrict__ q2c,
    const float* __restrict__ char_emb,
    const float* __restrict__ wconv, const float* __restrict__ bias,
    float* __restrict__ xout)
{
    const int P = C - K + 1;
    const int tid  = threadIdx.x;
    const int w    = tid >> 6;
    const int lane = tid & 63;
    const int f    = (lane < 50) ? lane : 49;

    __shared__ float2 wl2[32 * K * 50];
    __shared__ float  es[4][16 * 64];

    const int N2 = 32 * K * 50;
    for (int idx = tid; idx < N2; idx += 256) {
        int fr   = idx % 50;
        int rest = idx / 50;
        int k    = rest % K;
        int d2   = rest / K;
        const float* wp = wconv + (size_t)fr * CHD * K;
        wl2[idx] = make_float2(wp[d2 * K + k], wp[(d2 + 32) * K + k]);
    }
    const float bf = (lane < 50) ? bias[f] : 0.f;

#pragma unroll 1
    for (int t = 0; t < 8; ++t) {
        __syncthreads();
        const int tok    = blockIdx.x * 32 + w * 8 + t;
        const int branch = tok >> 12;
        const int tokl   = tok & (NT - 1);
        const int* qcrow = (branch ? q2c : q1c) + (size_t)tokl * C;

        int chv = (lane < 16) ? qcrow[lane] : 0;
        const int d2w = lane & 31, hw_ = lane >> 5;
#pragma unroll
        for (int r = 0; r < C; ++r) {
            int c = __shfl(chv, r, 64);
            es[w][r * 64 + d2w * 2 + hw_] = char_emb[(size_t)c * CHD + lane];
        }
        __syncthreads();

        const float2* es2 = (const float2*)es[w];
        float2 acc2[P];
#pragma unroll
        for (int p = 0; p < P; ++p) acc2[p] = make_float2(0.f, 0.f);

#pragma unroll 1
        for (int d2 = 0; d2 < 32; ++d2) {
            float2 e2[C];
#pragma unroll
            for (int r = 0; r < C; ++r) e2[r] = es2[r * 32 + d2];
#pragma unroll
            for (int k = 0; k < K; ++k) {
                float2 wv = wl2[(d2 * K + k) * 50 + f];
#pragma unroll
                for (int p = 0; p < P; ++p) {
                    acc2[p].x = fmaf(e2[p + k].x, wv.x, acc2[p].x);
                    acc2[p].y = fmaf(e2[p + k].y, wv.y, acc2[p].y);
                }
            }
        }
        float m = acc2[0].x + acc2[0].y;
#pragma unroll
        for (int p = 1; p < P; ++p) m = fmaxf(m, acc2[p].x + acc2[p].y);
        float r = fmaxf(0.f, m + bf);
        if (lane < 50)
            xout[(size_t)tok * D + EMB + OFF + lane] = r;
    }
}

// ---------------- kernel 2: highway (64x64 tile, BK=32, grid 8x128) ----------------
#define HBK 32
#define HPAD 68

__global__ __launch_bounds__(256, 4) void highway_kernel(
    const float* __restrict__ x, const float* __restrict__ W,
    const float* __restrict__ bvec, float* __restrict__ out)
{
    const int tid = threadIdx.x;
    const int tx = tid & 15, ty = tid >> 4;
    const int n0 = blockIdx.x * 64;
    const int m0 = blockIdx.y * 64;
    const int m4 = ty * 4, n4 = tx * 4;

    __shared__ float As[HBK][HPAD];
    __shared__ float Bs[HBK][HPAD];

    float acc[4][4] = {};
#pragma unroll 1
    for (int k0 = 0; k0 < D; k0 += HBK) {
        __syncthreads();
#pragma unroll
        for (int it = 0; it < 8; ++it) {
            int idx = tid + it * 256;
            int k = idx & 31, r = idx >> 5;
            int gk = k0 + k;
            As[k][r] = (gk < D) ? x[(size_t)(m0 + r) * D + gk] : 0.f;
            int gn = n0 + r;
            Bs[k][r] = (gk < D && gn < D) ? W[(size_t)gn * D + gk] : 0.f;
        }
        __syncthreads();
#pragma unroll 8
        for (int kk = 0; kk < HBK; ++kk) {
            float4 a = *(const float4*)&As[kk][m4];
            float4 bq = *(const float4*)&Bs[kk][n4];
            const float av[4] = {a.x, a.y, a.z, a.w};
            const float bv[4] = {bq.x, bq.y, bq.z, bq.w};
#pragma unroll
            for (int i = 0; i < 4; ++i)
#pragma unroll
                for (int j = 0; j < 4; ++j) acc[i][j] = fmaf(av[i], bv[j], acc[i][j]);
        }
    }
#pragma unroll
    for (int i = 0; i < 4; ++i) {
        const int m = m0 + m4 + i;
#pragma unroll
        for (int j = 0; j < 4; ++j) {
            const int n = n0 + n4 + j;
            if (n < D) {
                float y  = acc[i][j] + bvec[n];
                float g  = 1.f / (1.f + __expf(-y));
                float xo = x[(size_t)m * D + n];
                out[(size_t)m * D + n] = g * fmaxf(y, 0.f) + (1.f - g) * xo;
            }
        }
    }
}

// ---------------- kernel 3a: s1[i] = x_i.w1, s2[j] = x_j.w2 ----------------
// grid (NBH, 2), block 64
__global__ __launch_bounds__(64) void s12_kernel(
    const float* __restrict__ x, const float* __restrict__ attn_w,
    int layer, float* __restrict__ s12)
{
    const int bh    = blockIdx.x;
    const int which = blockIdx.y;
    const int lane  = threadIdx.x;
    const float* wv = attn_w + (size_t)layer * 3 * D + (size_t)which * D;
    const float* xb = x + (size_t)bh * L * D;

    float wr[8];
#pragma unroll
    for (int t = 0; t < 8; ++t) {
        int k = lane + t * 64;
        wr[t] = (k < D) ? wv[k] : 0.f;
    }
#pragma unroll 1
    for (int r = 0; r < L; ++r) {
        const float* xr = xb + (size_t)r * D;
        float p = 0.f;
#pragma unroll
        for (int t = 0; t < 8; ++t) {
            int k = lane + t * 64;
            if (k < D) p = fmaf(xr[k], wr[t], p);
        }
        p = wave_sum(p);
        if (lane == 0) s12[(size_t)bh * 128 + which * 64 + r] = p;
    }
}

// ---------------- kernel 3b: scores + softmax -> A ----------------
// grid (4 i-tiles, NBH), block 256; S[i][j] = sum_k X[i][k]*X[j][k]*w3[k] + s1 + s2 + b
#define APAD 68

__global__ __launch_bounds__(256, 4) void attn_score_kernel(
    const float* __restrict__ x,
    const int* __restrict__ q1_len, const int* __restrict__ q2_len,
    const float* __restrict__ attn_w, const float* __restrict__ attn_b,
    const float* __restrict__ s12, int layer, float* __restrict__ A_g)
{
    const int it = blockIdx.x, bh = blockIdx.y;
    const int i0 = it * 16;
    const int branch = bh >> 6, b = bh & 63;
    const int tid = threadIdx.x;
    const int tj = tid & 15, ti = tid >> 4;   // ti: i-row 0..15, tj: j-quad

    const float* xb  = x + (size_t)bh * L * D;
    const float* w3g = attn_w + (size_t)layer * 3 * D + 2 * D;

    __shared__ float As[32][17];
    __shared__ float Bs[32][APAD];
    __shared__ float Ssh[16][65];

    float acc[4] = {};
#pragma unroll 1
    for (int k0 = 0; k0 < D; k0 += 32) {
        __syncthreads();
        // stage Xi (16x32)
#pragma unroll
        for (int u = 0; u < 2; ++u) {
            int idx = tid + u * 256;
            int k = idx & 31, i = idx >> 5;
            int gk = k0 + k;
            As[k][i] = (gk < D) ? xb[(size_t)(i0 + i) * D + gk] : 0.f;
        }
        // stage Xj*w3 (64x32)
#pragma unroll
        for (int u = 0; u < 8; ++u) {
            int idx = tid + u * 256;
            int k = idx & 31, j = idx >> 5;
            int gk = k0 + k;
            Bs[k][j] = (gk < D) ? xb[(size_t)j * D + gk] * w3g[gk] : 0.f;
        }
        __syncthreads();
#pragma unroll 8
        for (int kk = 0; kk < 32; ++kk) {
            float a = As[kk][ti];
            float4 bq = *(const float4*)&Bs[kk][tj * 4];
            acc[0] = fmaf(a, bq.x, acc[0]);
            acc[1] = fmaf(a, bq.y, acc[1]);
            acc[2] = fmaf(a, bq.z, acc[2]);
            acc[3] = fmaf(a, bq.w, acc[3]);
        }
    }
#pragma unroll
    for (int q = 0; q < 4; ++q) Ssh[ti][tj * 4 + q] = acc[q];
    __syncthreads();

    const int   len  = (branch ? q2_len : q1_len)[b];
    const float bias = attn_b[layer];
    const float* s1p = s12 + (size_t)bh * 128;
    const float* s2p = s1p + 64;

    const int j  = tid & 63;
    const int rq = tid >> 6;
    const float s2v = s2p[j];
#pragma unroll
    for (int rr = 0; rr < 4; ++rr) {
        const int r = rq * 4 + rr;
        float s = Ssh[r][j] + s1p[i0 + r] + s2v + bias;
        if (j >= len) s = -1e-9f;            // reference's (buggy) mask value
        const float mx = wave_max(s);
        const float ev = __expf(s - mx);
        const float sm = wave_sum(ev);
        A_g[(size_t)bh * (L * L) + (size_t)(i0 + r) * L + j] = ev / sm;
    }
}

// ---------------- kernel 3c: out = A @ X (+ residual) ----------------
// grid (8 d-tiles, NBH), block 256
__global__ __launch_bounds__(256, 4) void attn_av_kernel(
    const float* __restrict__ x, const float* __restrict__ A_g,
    int add_resid, float* __restrict__ out)
{
    const int dt = blockIdx.x, bh = blockIdx.y;
    const int d0 = dt * 64;
    const int tid = threadIdx.x;
    const int td = tid & 15, ti = tid >> 4;
    const int d4 = td * 4, i4 = ti * 4;

    const float* xb = x + (size_t)bh * L * D;
    const float* Ab = A_g + (size_t)bh * (L * L);

    __shared__ float Ash[L][APAD];   // [k=j][i]
    __shared__ float Xc[L][APAD];    // [k=j][d]

    // stage A transposed: 4096 elems (coalesced global read, strided LDS write)
    for (int idx = tid; idx < L * L; idx += 256) {
        int j = idx & 63, i = idx >> 6;
        Ash[j][i] = Ab[(size_t)i * L + j];
    }
    // stage X chunk: 64 x 64
    for (int idx = tid; idx < L * 64; idx += 256) {
        int d = idx & 63, j = idx >> 6;
        int gd = d0 + d;
        Xc[j][d] = (gd < D) ? xb[(size_t)j * D + gd] : 0.f;
    }
    __syncthreads();

    float acc[4][4] = {};
#pragma unroll 8
    for (int k = 0; k < L; ++k) {
        float4 av = *(const float4*)&Ash[k][i4];
        float4 xv = *(const float4*)&Xc[k][d4];
        const float a[4] = {av.x, av.y, av.z, av.w};
        const float xr[4] = {xv.x, xv.y, xv.z, xv.w};
#pragma unroll
        for (int i = 0; i < 4; ++i)
#pragma unroll
            for (int d = 0; d < 4; ++d) acc[i][d] = fmaf(a[i], xr[d], acc[i][d]);
    }

    float* ob = out + (size_t)bh * L * D;
#pragma unroll
    for (int i = 0; i < 4; ++i) {
        const int gi = i4 + i;
#pragma unroll
        for (int d = 0; d < 4; ++d) {
            const int gd = d0 + d4 + d;
            if (gd < D) {
                float v = acc[i][d];
                if (add_resid) v += Xc[gi][d4 + d];
                ob[(size_t)gi * D + gd] = v;
            }
        }
    }
}

// ---------------- launch ----------------
extern "C" void kernel_launch(void* const* d_in, const int* in_sizes, int n_in,
                              void* d_out, int out_size, void* d_ws, size_t ws_size,
                              hipStream_t stream) {
    const int*   q1       = (const int*)  d_in[0];
    const int*   q2       = (const int*)  d_in[1];
    const int*   q1_len   = (const int*)  d_in[2];
    const int*   q2_len   = (const int*)  d_in[3];
    const int*   q1c      = (const int*)  d_in[4];
    const int*   q2c      = (const int*)  d_in[5];
    const float* word_emb = (const float*)d_in[6];
    const float* char_emb = (const float*)d_in[7];
    const float* w3       = (const float*)d_in[8];
    const float* b3       = (const float*)d_in[9];
    const float* w4       = (const float*)d_in[10];
    const float* b4       = (const float*)d_in[11];
    const float* w5       = (const float*)d_in[12];
    const float* b5       = (const float*)d_in[13];
    const float* hw_w     = (const float*)d_in[14];
    const float* hw_b     = (const float*)d_in[15];
    const float* attn_w   = (const float*)d_in[16];
    const float* attn_b   = (const float*)d_in[17];
    float* out = (float*)d_out;

    float* buf0  = (float*)d_ws;                       // 2*NT*D
    float* buf1  = buf0 + (size_t)2 * NT * D;          // 2*NT*D
    float* A_g   = buf1 + (size_t)2 * NT * D;          // NBH*L*L
    float* s12_g = A_g + (size_t)NBH * L * L;          // NBH*128

    // 1. embeddings + char conv -> buf0
    wordcopy_kernel<<<2 * NT / 4, 256, 0, stream>>>(q1, q2, word_emb, buf0);
    conv_kernel<3, 0>  <<<256, 256, 0, stream>>>(q1c, q2c, char_emb, w3, b3, buf0);
    conv_kernel<4, 50> <<<256, 256, 0, stream>>>(q1c, q2c, char_emb, w4, b4, buf0);
    conv_kernel<5, 100><<<256, 256, 0, stream>>>(q1c, q2c, char_emb, w5, b5, buf0);

    // 2. highway x2
    dim3 hgrid(8, (2 * NT) / 64);
    highway_kernel<<<hgrid, 256, 0, stream>>>(buf0, hw_w, hw_b, buf1);
    highway_kernel<<<hgrid, 256, 0, stream>>>(buf1, hw_w, hw_b, buf0);

    // 3. attn layer 0: x0 = buf0 -> x1 = buf1 (residual fused)
    s12_kernel<<<dim3(NBH, 2), 64, 0, stream>>>(buf0, attn_w, 0, s12_g);
    attn_score_kernel<<<dim3(4, NBH), 256, 0, stream>>>(
        buf0, q1_len, q2_len, attn_w, attn_b, s12_g, 0, A_g);
    attn_av_kernel<<<dim3(8, NBH), 256, 0, stream>>>(buf0, A_g, 1, buf1);

    // 4. attn layer 1: x1 = buf1 -> att -> d_out
    s12_kernel<<<dim3(NBH, 2), 64, 0, stream>>>(buf1, attn_w, 1, s12_g);
    attn_score_kernel<<<dim3(4, NBH), 256, 0, stream>>>(
        buf1, q1_len, q2_len, attn_w, attn_b, s12_g, 1, A_g);
    attn_av_kernel<<<dim3(8, NBH), 256, 0, stream>>>(buf1, A_g, 0, out);
}

// Round 5
// 776.355 us; speedup vs baseline: 1.5237x; 1.2764x over previous
//
#include <hip/hip_runtime.h>
#include <math.h>

// ---- problem constants ----
#define B   64
#define L   64
#define C   16
#define CHD 64
#define EMB 300
#define D   450       // EMB + 3*50
#define NT  (B*L)     // 4096 tokens per branch
#define NBH 128       // 2 branches * 64 batch

// ---------------- wave helpers (wave64) ----------------
__device__ inline float wave_sum(float v) {
#pragma unroll
    for (int o = 32; o; o >>= 1) v += __shfl_xor(v, o, 64);
    return v;
}
__device__ inline float wave_max(float v) {
#pragma unroll
    for (int o = 32; o; o >>= 1) v = fmaxf(v, __shfl_xor(v, o, 64));
    return v;
}

// ---------------- kernel 0: word embedding copy ----------------
__global__ __launch_bounds__(256) void wordcopy_kernel(
    const int* __restrict__ q1, const int* __restrict__ q2,
    const float* __restrict__ word_emb, float* __restrict__ xout)
{
    const int tid = threadIdx.x;
#pragma unroll
    for (int t = 0; t < 4; ++t) {
        const int tok    = blockIdx.x * 4 + t;
        const int branch = tok >> 12;
        const int tokl   = tok & (NT - 1);
        const int w      = (branch ? q2 : q1)[tokl];
        const float* src = word_emb + (size_t)w * EMB;
        float*       dst = xout + (size_t)tok * D;
        for (int d = tid; d < EMB; d += 256) dst[d] = src[d];
    }
}

// ---------------- kernel 1: char conv, LDS weights ----------------
template <int K, int OFF>
__global__ __launch_bounds__(256) void conv_kernel(
    const int* __restrict__ q1c, const int* __restrict__ q2c,
    const float* __restrict__ char_emb,
    const float* __restrict__ wconv, const float* __restrict__ bias,
    float* __restrict__ xout)
{
    const int P = C - K + 1;
    const int tid  = threadIdx.x;
    const int w    = tid >> 6;
    const int lane = tid & 63;
    const int f    = (lane < 50) ? lane : 49;

    __shared__ float2 wl2[32 * K * 50];
    __shared__ float  es[4][16 * 64];

    const int N2 = 32 * K * 50;
    for (int idx = tid; idx < N2; idx += 256) {
        int fr   = idx % 50;
        int rest = idx / 50;
        int k    = rest % K;
        int d2   = rest / K;
        const float* wp = wconv + (size_t)fr * CHD * K;
        wl2[idx] = make_float2(wp[d2 * K + k], wp[(d2 + 32) * K + k]);
    }
    const float bf = (lane < 50) ? bias[f] : 0.f;

#pragma unroll 1
    for (int t = 0; t < 8; ++t) {
        __syncthreads();
        const int tok    = blockIdx.x * 32 + w * 8 + t;
        const int branch = tok >> 12;
        const int tokl   = tok & (NT - 1);
        const int* qcrow = (branch ? q2c : q1c) + (size_t)tokl * C;

        int chv = (lane < 16) ? qcrow[lane] : 0;
        const int d2w = lane & 31, hw_ = lane >> 5;
#pragma unroll
        for (int r = 0; r < C; ++r) {
            int c = __shfl(chv, r, 64);
            es[w][r * 64 + d2w * 2 + hw_] = char_emb[(size_t)c * CHD + lane];
        }
        __syncthreads();

        const float2* es2 = (const float2*)es[w];
        float2 acc2[P];
#pragma unroll
        for (int p = 0; p < P; ++p) acc2[p] = make_float2(0.f, 0.f);

#pragma unroll 1
        for (int d2 = 0; d2 < 32; ++d2) {
            float2 e2[C];
#pragma unroll
            for (int r = 0; r < C; ++r) e2[r] = es2[r * 32 + d2];
#pragma unroll
            for (int k = 0; k < K; ++k) {
                float2 wv = wl2[(d2 * K + k) * 50 + f];
#pragma unroll
                for (int p = 0; p < P; ++p) {
                    acc2[p].x = fmaf(e2[p + k].x, wv.x, acc2[p].x);
                    acc2[p].y = fmaf(e2[p + k].y, wv.y, acc2[p].y);
                }
            }
        }
        float m = acc2[0].x + acc2[0].y;
#pragma unroll
        for (int p = 1; p < P; ++p) m = fmaxf(m, acc2[p].x + acc2[p].y);
        float r = fmaxf(0.f, m + bf);
        if (lane < 50)
            xout[(size_t)tok * D + EMB + OFF + lane] = r;
    }
}

// ---------------- kernel 2: highway (64x64 tile, BK=32, grid 8x128) ----------------
#define HBK 32
#define HPAD 68

__global__ __launch_bounds__(256, 4) void highway_kernel(
    const float* __restrict__ x, const float* __restrict__ W,
    const float* __restrict__ bvec, float* __restrict__ out)
{
    const int tid = threadIdx.x;
    const int tx = tid & 15, ty = tid >> 4;
    const int n0 = blockIdx.x * 64;
    const int m0 = blockIdx.y * 64;
    const int m4 = ty * 4, n4 = tx * 4;

    __shared__ float As[HBK][HPAD];
    __shared__ float Bs[HBK][HPAD];

    float acc[4][4] = {};
#pragma unroll 1
    for (int k0 = 0; k0 < D; k0 += HBK) {
        __syncthreads();
#pragma unroll
        for (int it = 0; it < 8; ++it) {
            int idx = tid + it * 256;
            int k = idx & 31, r = idx >> 5;
            int gk = k0 + k;
            As[k][r] = (gk < D) ? x[(size_t)(m0 + r) * D + gk] : 0.f;
            int gn = n0 + r;
            Bs[k][r] = (gk < D && gn < D) ? W[(size_t)gn * D + gk] : 0.f;
        }
        __syncthreads();
#pragma unroll 8
        for (int kk = 0; kk < HBK; ++kk) {
            float4 a = *(const float4*)&As[kk][m4];
            float4 bq = *(const float4*)&Bs[kk][n4];
            const float av[4] = {a.x, a.y, a.z, a.w};
            const float bv[4] = {bq.x, bq.y, bq.z, bq.w};
#pragma unroll
            for (int i = 0; i < 4; ++i)
#pragma unroll
                for (int j = 0; j < 4; ++j) acc[i][j] = fmaf(av[i], bv[j], acc[i][j]);
        }
    }
#pragma unroll
    for (int i = 0; i < 4; ++i) {
        const int m = m0 + m4 + i;
#pragma unroll
        for (int j = 0; j < 4; ++j) {
            const int n = n0 + n4 + j;
            if (n < D) {
                float y  = acc[i][j] + bvec[n];
                float g  = 1.f / (1.f + __expf(-y));
                float xo = x[(size_t)m * D + n];
                out[(size_t)m * D + n] = g * fmaxf(y, 0.f) + (1.f - g) * xo;
            }
        }
    }
}

// ---------------- kernel 3b: scores + softmax -> A (s1/s2 fused in) ----------------
// grid (4 i-tiles, NBH), block 256; S[i][j] = sum_k X[i][k]*X[j][k]*w3[k] + s1 + s2 + b
#define APAD 68

__global__ __launch_bounds__(256, 4) void attn_score_kernel(
    const float* __restrict__ x,
    const int* __restrict__ q1_len, const int* __restrict__ q2_len,
    const float* __restrict__ attn_w, const float* __restrict__ attn_b,
    int layer, float* __restrict__ A_g)
{
    const int it = blockIdx.x, bh = blockIdx.y;
    const int i0 = it * 16;
    const int branch = bh >> 6, b = bh & 63;
    const int tid = threadIdx.x;
    const int tj = tid & 15, ti = tid >> 4;   // ti: i-row 0..15, tj: j-quad
    const int wv_  = tid >> 6;                // wave id 0..3
    const int lane = tid & 63;

    const float* xb  = x + (size_t)bh * L * D;
    const float* wb  = attn_w + (size_t)layer * 3 * D;   // w1 | w2 | w3
    const float* w3g = wb + 2 * D;

    __shared__ float As[32][17];
    __shared__ float Bs[32][APAD];
    __shared__ float Ssh[16][65];
    __shared__ float s1s[16], s2s[64];

    // ---- fused s1/s2: 80 dot products of length D, 20 per wave ----
#pragma unroll 1
    for (int p = wv_; p < 80; p += 4) {
        const int    row  = (p < 16) ? (i0 + p) : (p - 16);
        const float* wsel = (p < 16) ? wb : (wb + D);
        const float* xr   = xb + (size_t)row * D;
        float s = 0.f;
#pragma unroll
        for (int t = 0; t < 8; ++t) {
            int k = lane + t * 64;
            if (k < D) s = fmaf(xr[k], wsel[k], s);
        }
        s = wave_sum(s);
        if (lane == 0) { if (p < 16) s1s[p] = s; else s2s[p - 16] = s; }
    }

    float acc[4] = {};
#pragma unroll 1
    for (int k0 = 0; k0 < D; k0 += 32) {
        __syncthreads();
        // stage Xi (16x32)
#pragma unroll
        for (int u = 0; u < 2; ++u) {
            int idx = tid + u * 256;
            int k = idx & 31, i = idx >> 5;
            int gk = k0 + k;
            As[k][i] = (gk < D) ? xb[(size_t)(i0 + i) * D + gk] : 0.f;
        }
        // stage Xj*w3 (64x32)
#pragma unroll
        for (int u = 0; u < 8; ++u) {
            int idx = tid + u * 256;
            int k = idx & 31, j = idx >> 5;
            int gk = k0 + k;
            Bs[k][j] = (gk < D) ? xb[(size_t)j * D + gk] * w3g[gk] : 0.f;
        }
        __syncthreads();
#pragma unroll 8
        for (int kk = 0; kk < 32; ++kk) {
            float a = As[kk][ti];
            float4 bq = *(const float4*)&Bs[kk][tj * 4];
            acc[0] = fmaf(a, bq.x, acc[0]);
            acc[1] = fmaf(a, bq.y, acc[1]);
            acc[2] = fmaf(a, bq.z, acc[2]);
            acc[3] = fmaf(a, bq.w, acc[3]);
        }
    }
#pragma unroll
    for (int q = 0; q < 4; ++q) Ssh[ti][tj * 4 + q] = acc[q];
    __syncthreads();

    const int   len  = (branch ? q2_len : q1_len)[b];
    const float bias = attn_b[layer];

    const int j  = tid & 63;
    const int rq = tid >> 6;
    const float s2v = s2s[j];
#pragma unroll
    for (int rr = 0; rr < 4; ++rr) {
        const int r = rq * 4 + rr;
        float s = Ssh[r][j] + s1s[r] + s2v + bias;
        if (j >= len) s = -1e-9f;            // reference's (buggy) mask value
        const float mx = wave_max(s);
        const float ev = __expf(s - mx);
        const float sm = wave_sum(ev);
        A_g[(size_t)bh * (L * L) + (size_t)(i0 + r) * L + j] = ev / sm;
    }
}

// ---------------- kernel 3c: out = A @ X (+ residual) ----------------
// grid (8 d-tiles, NBH), block 256
__global__ __launch_bounds__(256, 4) void attn_av_kernel(
    const float* __restrict__ x, const float* __restrict__ A_g,
    int add_resid, float* __restrict__ out)
{
    const int dt = blockIdx.x, bh = blockIdx.y;
    const int d0 = dt * 64;
    const int tid = threadIdx.x;
    const int td = tid & 15, ti = tid >> 4;
    const int d4 = td * 4, i4 = ti * 4;

    const float* xb = x + (size_t)bh * L * D;
    const float* Ab = A_g + (size_t)bh * (L * L);

    __shared__ float Ash[L][APAD];   // [k=j][i]
    __shared__ float Xc[L][APAD];    // [k=j][d]

    // stage A transposed
    for (int idx = tid; idx < L * L; idx += 256) {
        int j = idx & 63, i = idx >> 6;
        Ash[j][i] = Ab[(size_t)i * L + j];
    }
    // stage X chunk: 64 x 64
    for (int idx = tid; idx < L * 64; idx += 256) {
        int d = idx & 63, j = idx >> 6;
        int gd = d0 + d;
        Xc[j][d] = (gd < D) ? xb[(size_t)j * D + gd] : 0.f;
    }
    __syncthreads();

    float acc[4][4] = {};
#pragma unroll 8
    for (int k = 0; k < L; ++k) {
        float4 av = *(const float4*)&Ash[k][i4];
        float4 xv = *(const float4*)&Xc[k][d4];
        const float a[4] = {av.x, av.y, av.z, av.w};
        const float xr[4] = {xv.x, xv.y, xv.z, xv.w};
#pragma unroll
        for (int i = 0; i < 4; ++i)
#pragma unroll
            for (int d = 0; d < 4; ++d) acc[i][d] = fmaf(a[i], xr[d], acc[i][d]);
    }

    float* ob = out + (size_t)bh * L * D;
#pragma unroll
    for (int i = 0; i < 4; ++i) {
        const int gi = i4 + i;
#pragma unroll
        for (int d = 0; d < 4; ++d) {
            const int gd = d0 + d4 + d;
            if (gd < D) {
                float v = acc[i][d];
                if (add_resid) v += Xc[gi][d4 + d];
                ob[(size_t)gi * D + gd] = v;
            }
        }
    }
}

// ---------------- launch ----------------
extern "C" void kernel_launch(void* const* d_in, const int* in_sizes, int n_in,
                              void* d_out, int out_size, void* d_ws, size_t ws_size,
                              hipStream_t stream) {
    const int*   q1       = (const int*)  d_in[0];
    const int*   q2       = (const int*)  d_in[1];
    const int*   q1_len   = (const int*)  d_in[2];
    const int*   q2_len   = (const int*)  d_in[3];
    const int*   q1c      = (const int*)  d_in[4];
    const int*   q2c      = (const int*)  d_in[5];
    const float* word_emb = (const float*)d_in[6];
    const float* char_emb = (const float*)d_in[7];
    const float* w3       = (const float*)d_in[8];
    const float* b3       = (const float*)d_in[9];
    const float* w4       = (const float*)d_in[10];
    const float* b4       = (const float*)d_in[11];
    const float* w5       = (const float*)d_in[12];
    const float* b5       = (const float*)d_in[13];
    const float* hw_w     = (const float*)d_in[14];
    const float* hw_b     = (const float*)d_in[15];
    const float* attn_w   = (const float*)d_in[16];
    const float* attn_b   = (const float*)d_in[17];
    float* out = (float*)d_out;

    float* buf0  = (float*)d_ws;                       // 2*NT*D
    float* buf1  = buf0 + (size_t)2 * NT * D;          // 2*NT*D
    float* A_g   = buf1 + (size_t)2 * NT * D;          // NBH*L*L

    // 1. embeddings + char conv -> buf0
    wordcopy_kernel<<<2 * NT / 4, 256, 0, stream>>>(q1, q2, word_emb, buf0);
    conv_kernel<3, 0>  <<<256, 256, 0, stream>>>(q1c, q2c, char_emb, w3, b3, buf0);
    conv_kernel<4, 50> <<<256, 256, 0, stream>>>(q1c, q2c, char_emb, w4, b4, buf0);
    conv_kernel<5, 100><<<256, 256, 0, stream>>>(q1c, q2c, char_emb, w5, b5, buf0);

    // 2. highway x2
    dim3 hgrid(8, (2 * NT) / 64);
    highway_kernel<<<hgrid, 256, 0, stream>>>(buf0, hw_w, hw_b, buf1);
    highway_kernel<<<hgrid, 256, 0, stream>>>(buf1, hw_w, hw_b, buf0);

    // 3. attn layer 0: x0 = buf0 -> x1 = buf1 (residual fused)
    attn_score_kernel<<<dim3(4, NBH), 256, 0, stream>>>(
        buf0, q1_len, q2_len, attn_w, attn_b, 0, A_g);
    attn_av_kernel<<<dim3(8, NBH), 256, 0, stream>>>(buf0, A_g, 1, buf1);

    // 4. attn layer 1: x1 = buf1 -> att -> d_out
    attn_score_kernel<<<dim3(4, NBH), 256, 0, stream>>>(
        buf1, q1_len, q2_len, attn_w, attn_b, 1, A_g);
    attn_av_kernel<<<dim3(8, NBH), 256, 0, stream>>>(buf1, A_g, 0, out);
}

// Round 6
// 611.358 us; speedup vs baseline: 1.9349x; 1.2699x over previous
//
#include <hip/hip_runtime.h>
#include <math.h>

// ---- problem constants ----
#define B   64
#define L   64
#define C   16
#define CHD 64
#define EMB 300
#define D   450       // EMB + 3*50
#define DP  480       // padded bf16 row stride (mult of 32, 16B-aligned rows)
#define NT  (B*L)     // 4096 tokens per branch
#define NBH 128       // 2 branches * 64 batch

typedef short bf16x8 __attribute__((ext_vector_type(8)));
typedef float f32x4  __attribute__((ext_vector_type(4)));
typedef unsigned short ushort_t;

// ---------------- helpers ----------------
__device__ inline float wave_sum(float v) {
#pragma unroll
    for (int o = 32; o; o >>= 1) v += __shfl_xor(v, o, 64);
    return v;
}
__device__ inline float wave_max(float v) {
#pragma unroll
    for (int o = 32; o; o >>= 1) v = fmaxf(v, __shfl_xor(v, o, 64));
    return v;
}
__device__ inline ushort_t f2b(float f) {   // RNE float->bf16
    union { float f; unsigned u; } c; c.f = f;
    unsigned r = c.u + 0x7FFFu + ((c.u >> 16) & 1u);
    return (ushort_t)(r >> 16);
}

// ---------------- kernel 0: word embedding copy (f32 + bf16, zero-pad tail) ----------------
__global__ __launch_bounds__(256) void wordcopy_kernel(
    const int* __restrict__ q1, const int* __restrict__ q2,
    const float* __restrict__ word_emb, float* __restrict__ xout,
    ushort_t* __restrict__ xb16)
{
    const int tid = threadIdx.x;
#pragma unroll
    for (int t = 0; t < 4; ++t) {
        const int tok    = blockIdx.x * 4 + t;
        const int branch = tok >> 12;
        const int tokl   = tok & (NT - 1);
        const int w      = (branch ? q2 : q1)[tokl];
        const float* src = word_emb + (size_t)w * EMB;
        float*     dst   = xout + (size_t)tok * D;
        ushort_t*  dstb  = xb16 + (size_t)tok * DP;
        for (int d = tid; d < EMB; d += 256) {
            float v = src[d];
            dst[d] = v;
            dstb[d] = f2b(v);
        }
        // zero-pad bf16 tail (k = 450..479)
        if (tid < DP - D) dstb[D + tid] = 0;
    }
}

// ---------------- kernel 1: char conv (f32 + bf16 out), 8 tokens/block ----------------
template <int K, int OFF>
__global__ __launch_bounds__(256) void conv_kernel(
    const int* __restrict__ q1c, const int* __restrict__ q2c,
    const float* __restrict__ char_emb,
    const float* __restrict__ wconv, const float* __restrict__ bias,
    float* __restrict__ xout, ushort_t* __restrict__ xb16)
{
    const int P = C - K + 1;
    const int tid  = threadIdx.x;
    const int w    = tid >> 6;
    const int lane = tid & 63;
    const int f    = (lane < 50) ? lane : 49;

    __shared__ float2 wl2[32 * K * 50];
    __shared__ float  es[4][16 * 64];

    const int N2 = 32 * K * 50;
    for (int idx = tid; idx < N2; idx += 256) {
        int fr   = idx % 50;
        int rest = idx / 50;
        int k    = rest % K;
        int d2   = rest / K;
        const float* wp = wconv + (size_t)fr * CHD * K;
        wl2[idx] = make_float2(wp[d2 * K + k], wp[(d2 + 32) * K + k]);
    }
    const float bf = (lane < 50) ? bias[f] : 0.f;

#pragma unroll 1
    for (int t = 0; t < 2; ++t) {
        __syncthreads();
        const int tok    = blockIdx.x * 8 + w * 2 + t;
        const int branch = tok >> 12;
        const int tokl   = tok & (NT - 1);
        const int* qcrow = (branch ? q2c : q1c) + (size_t)tokl * C;

        int chv = (lane < 16) ? qcrow[lane] : 0;
        const int d2w = lane & 31, hw_ = lane >> 5;
#pragma unroll
        for (int r = 0; r < C; ++r) {
            int c = __shfl(chv, r, 64);
            es[w][r * 64 + d2w * 2 + hw_] = char_emb[(size_t)c * CHD + lane];
        }
        __syncthreads();

        const float2* es2 = (const float2*)es[w];
        float2 acc2[P];
#pragma unroll
        for (int p = 0; p < P; ++p) acc2[p] = make_float2(0.f, 0.f);

#pragma unroll 1
        for (int d2 = 0; d2 < 32; ++d2) {
            float2 e2[C];
#pragma unroll
            for (int r = 0; r < C; ++r) e2[r] = es2[r * 32 + d2];
#pragma unroll
            for (int k = 0; k < K; ++k) {
                float2 wv = wl2[(d2 * K + k) * 50 + f];
#pragma unroll
                for (int p = 0; p < P; ++p) {
                    acc2[p].x = fmaf(e2[p + k].x, wv.x, acc2[p].x);
                    acc2[p].y = fmaf(e2[p + k].y, wv.y, acc2[p].y);
                }
            }
        }
        float m = acc2[0].x + acc2[0].y;
#pragma unroll
        for (int p = 1; p < P; ++p) m = fmaxf(m, acc2[p].x + acc2[p].y);
        float r = fmaxf(0.f, m + bf);
        if (lane < 50) {
            xout[(size_t)tok * D + EMB + OFF + lane] = r;
            xb16[(size_t)tok * DP + EMB + OFF + lane] = f2b(r);
        }
    }
}

// ---------------- kernel 1b: W -> bf16 padded image (512 x 480, zero-filled) ----------------
__global__ __launch_bounds__(256) void wconv_kernel(
    const float* __restrict__ W, ushort_t* __restrict__ Wb16)
{
    int idx = blockIdx.x * 256 + threadIdx.x;        // 512*480 = 245760
    if (idx >= 512 * DP) return;
    int n = idx / DP, k = idx - n * DP;
    float v = (n < D && k < D) ? W[(size_t)n * D + k] : 0.f;
    Wb16[idx] = f2b(v);
}

// ---------------- kernel 2: highway via bf16 MFMA (no LDS) ----------------
// grid (8 n-tiles, 128 m-tiles), block 256 = 4 waves in 2x2; wave tile 32x32.
// y = x @ W^T: A[m][k]=x, B "rows" are W[n][k] -> both load directly in operand layout.
template <bool EMIT>
__global__ __launch_bounds__(256) void highway_mfma_kernel(
    const ushort_t* __restrict__ xb16, const float* __restrict__ xf32,
    const ushort_t* __restrict__ Wb16, const float* __restrict__ bvec,
    float* __restrict__ out, ushort_t* __restrict__ outb16)
{
    const int tid  = threadIdx.x;
    const int wv   = tid >> 6;
    const int lane = tid & 63;
    const int wm = wv >> 1, wn = wv & 1;
    const int m0 = blockIdx.y * 64 + wm * 32;
    const int n0 = blockIdx.x * 64 + wn * 32;
    const int lm = lane & 15, quad = lane >> 4;

    const ushort_t* ax = xb16 + (size_t)(m0 + lm) * DP + quad * 8;
    const ushort_t* bw = Wb16 + (size_t)(n0 + lm) * DP + quad * 8;

    f32x4 acc[2][2];
#pragma unroll
    for (int i = 0; i < 2; ++i)
#pragma unroll
        for (int j = 0; j < 2; ++j) acc[i][j] = (f32x4){0.f, 0.f, 0.f, 0.f};

#pragma unroll 1
    for (int k0 = 0; k0 < DP; k0 += 32) {
        bf16x8 a0 = *(const bf16x8*)(ax + k0);
        bf16x8 a1 = *(const bf16x8*)(ax + (size_t)16 * DP + k0);
        bf16x8 b0 = *(const bf16x8*)(bw + k0);
        bf16x8 b1 = *(const bf16x8*)(bw + (size_t)16 * DP + k0);
        acc[0][0] = __builtin_amdgcn_mfma_f32_16x16x32_bf16(a0, b0, acc[0][0], 0, 0, 0);
        acc[0][1] = __builtin_amdgcn_mfma_f32_16x16x32_bf16(a0, b1, acc[0][1], 0, 0, 0);
        acc[1][0] = __builtin_amdgcn_mfma_f32_16x16x32_bf16(a1, b0, acc[1][0], 0, 0, 0);
        acc[1][1] = __builtin_amdgcn_mfma_f32_16x16x32_bf16(a1, b1, acc[1][1], 0, 0, 0);
    }

    // epilogue: C/D layout col = lane&15, row = quad*4 + reg
#pragma unroll
    for (int nt = 0; nt < 2; ++nt) {
        const int n = n0 + nt * 16 + lm;
        const bool nval = (n < D);
        const float bv = nval ? bvec[n] : 0.f;
#pragma unroll
        for (int mt = 0; mt < 2; ++mt) {
#pragma unroll
            for (int r = 0; r < 4; ++r) {
                const int m = m0 + mt * 16 + quad * 4 + r;
                float y = acc[mt][nt][r] + bv;
                float g = 1.f / (1.f + __expf(-y));
                float o = 0.f;
                if (nval) {
                    float xo = xf32[(size_t)m * D + n];
                    o = g * fmaxf(y, 0.f) + (1.f - g) * xo;
                    out[(size_t)m * D + n] = o;
                }
                if (EMIT && n < DP)
                    outb16[(size_t)m * DP + n] = f2b(nval ? o : 0.f);
            }
        }
    }
}

// ---------------- kernel 3b: scores + softmax -> A (s1/s2 fused in) ----------------
#define APAD 68

__global__ __launch_bounds__(256, 4) void attn_score_kernel(
    const float* __restrict__ x,
    const int* __restrict__ q1_len, const int* __restrict__ q2_len,
    const float* __restrict__ attn_w, const float* __restrict__ attn_b,
    int layer, float* __restrict__ A_g)
{
    const int it = blockIdx.x, bh = blockIdx.y;
    const int i0 = it * 16;
    const int branch = bh >> 6, b = bh & 63;
    const int tid = threadIdx.x;
    const int tj = tid & 15, ti = tid >> 4;
    const int wv_  = tid >> 6;
    const int lane = tid & 63;

    const float* xb  = x + (size_t)bh * L * D;
    const float* wb  = attn_w + (size_t)layer * 3 * D;   // w1 | w2 | w3
    const float* w3g = wb + 2 * D;

    __shared__ float As[32][17];
    __shared__ float Bs[32][APAD];
    __shared__ float Ssh[16][65];
    __shared__ float s1s[16], s2s[64];

#pragma unroll 1
    for (int p = wv_; p < 80; p += 4) {
        const int    row  = (p < 16) ? (i0 + p) : (p - 16);
        const float* wsel = (p < 16) ? wb : (wb + D);
        const float* xr   = xb + (size_t)row * D;
        float s = 0.f;
#pragma unroll
        for (int t = 0; t < 8; ++t) {
            int k = lane + t * 64;
            if (k < D) s = fmaf(xr[k], wsel[k], s);
        }
        s = wave_sum(s);
        if (lane == 0) { if (p < 16) s1s[p] = s; else s2s[p - 16] = s; }
    }

    float acc[4] = {};
#pragma unroll 1
    for (int k0 = 0; k0 < D; k0 += 32) {
        __syncthreads();
#pragma unroll
        for (int u = 0; u < 2; ++u) {
            int idx = tid + u * 256;
            int k = idx & 31, i = idx >> 5;
            int gk = k0 + k;
            As[k][i] = (gk < D) ? xb[(size_t)(i0 + i) * D + gk] : 0.f;
        }
#pragma unroll
        for (int u = 0; u < 8; ++u) {
            int idx = tid + u * 256;
            int k = idx & 31, j = idx >> 5;
            int gk = k0 + k;
            Bs[k][j] = (gk < D) ? xb[(size_t)j * D + gk] * w3g[gk] : 0.f;
        }
        __syncthreads();
#pragma unroll 8
        for (int kk = 0; kk < 32; ++kk) {
            float a = As[kk][ti];
            float4 bq = *(const float4*)&Bs[kk][tj * 4];
            acc[0] = fmaf(a, bq.x, acc[0]);
            acc[1] = fmaf(a, bq.y, acc[1]);
            acc[2] = fmaf(a, bq.z, acc[2]);
            acc[3] = fmaf(a, bq.w, acc[3]);
        }
    }
#pragma unroll
    for (int q = 0; q < 4; ++q) Ssh[ti][tj * 4 + q] = acc[q];
    __syncthreads();

    const int   len  = (branch ? q2_len : q1_len)[b];
    const float bias = attn_b[layer];

    const int j  = tid & 63;
    const int rq = tid >> 6;
    const float s2v = s2s[j];
#pragma unroll
    for (int rr = 0; rr < 4; ++rr) {
        const int r = rq * 4 + rr;
        float s = Ssh[r][j] + s1s[r] + s2v + bias;
        if (j >= len) s = -1e-9f;            // reference's (buggy) mask value
        const float mx = wave_max(s);
        const float ev = __expf(s - mx);
        const float sm = wave_sum(ev);
        A_g[(size_t)bh * (L * L) + (size_t)(i0 + r) * L + j] = ev / sm;
    }
}

// ---------------- kernel 3c: out = A @ X (+ residual) ----------------
__global__ __launch_bounds__(256, 4) void attn_av_kernel(
    const float* __restrict__ x, const float* __restrict__ A_g,
    int add_resid, float* __restrict__ out)
{
    const int dt = blockIdx.x, bh = blockIdx.y;
    const int d0 = dt * 64;
    const int tid = threadIdx.x;
    const int td = tid & 15, ti = tid >> 4;
    const int d4 = td * 4, i4 = ti * 4;

    const float* xb = x + (size_t)bh * L * D;
    const float* Ab = A_g + (size_t)bh * (L * L);

    __shared__ float Ash[L][APAD];   // [k=j][i]
    __shared__ float Xc[L][APAD];    // [k=j][d]

    for (int idx = tid; idx < L * L; idx += 256) {
        int j = idx & 63, i = idx >> 6;
        Ash[j][i] = Ab[(size_t)i * L + j];
    }
    for (int idx = tid; idx < L * 64; idx += 256) {
        int d = idx & 63, j = idx >> 6;
        int gd = d0 + d;
        Xc[j][d] = (gd < D) ? xb[(size_t)j * D + gd] : 0.f;
    }
    __syncthreads();

    float acc[4][4] = {};
#pragma unroll 8
    for (int k = 0; k < L; ++k) {
        float4 av = *(const float4*)&Ash[k][i4];
        float4 xv = *(const float4*)&Xc[k][d4];
        const float a[4] = {av.x, av.y, av.z, av.w};
        const float xr[4] = {xv.x, xv.y, xv.z, xv.w};
#pragma unroll
        for (int i = 0; i < 4; ++i)
#pragma unroll
            for (int d = 0; d < 4; ++d) acc[i][d] = fmaf(a[i], xr[d], acc[i][d]);
    }

    float* ob = out + (size_t)bh * L * D;
#pragma unroll
    for (int i = 0; i < 4; ++i) {
        const int gi = i4 + i;
#pragma unroll
        for (int d = 0; d < 4; ++d) {
            const int gd = d0 + d4 + d;
            if (gd < D) {
                float v = acc[i][d];
                if (add_resid) v += Xc[gi][d4 + d];
                ob[(size_t)gi * D + gd] = v;
            }
        }
    }
}

// ---------------- launch ----------------
extern "C" void kernel_launch(void* const* d_in, const int* in_sizes, int n_in,
                              void* d_out, int out_size, void* d_ws, size_t ws_size,
                              hipStream_t stream) {
    const int*   q1       = (const int*)  d_in[0];
    const int*   q2       = (const int*)  d_in[1];
    const int*   q1_len   = (const int*)  d_in[2];
    const int*   q2_len   = (const int*)  d_in[3];
    const int*   q1c      = (const int*)  d_in[4];
    const int*   q2c      = (const int*)  d_in[5];
    const float* word_emb = (const float*)d_in[6];
    const float* char_emb = (const float*)d_in[7];
    const float* w3       = (const float*)d_in[8];
    const float* b3       = (const float*)d_in[9];
    const float* w4       = (const float*)d_in[10];
    const float* b4       = (const float*)d_in[11];
    const float* w5       = (const float*)d_in[12];
    const float* b5       = (const float*)d_in[13];
    const float* hw_w     = (const float*)d_in[14];
    const float* hw_b     = (const float*)d_in[15];
    const float* attn_w   = (const float*)d_in[16];
    const float* attn_b   = (const float*)d_in[17];
    float* out = (float*)d_out;

    float*    buf0  = (float*)d_ws;                        // 2*NT*D f32
    float*    buf1  = buf0 + (size_t)2 * NT * D;           // 2*NT*D f32
    float*    A_g   = buf1 + (size_t)2 * NT * D;           // NBH*L*L f32
    ushort_t* xb16a = (ushort_t*)(A_g + (size_t)NBH * L * L);     // 2*NT*DP bf16
    ushort_t* xb16b = xb16a + (size_t)2 * NT * DP;                // 2*NT*DP bf16
    ushort_t* Wb16  = xb16b + (size_t)2 * NT * DP;                // 512*DP bf16

    // 1. embeddings + char conv -> buf0 (f32) + xb16a (bf16, padded)
    wordcopy_kernel<<<2 * NT / 4, 256, 0, stream>>>(q1, q2, word_emb, buf0, xb16a);
    conv_kernel<3, 0>  <<<1024, 256, 0, stream>>>(q1c, q2c, char_emb, w3, b3, buf0, xb16a);
    conv_kernel<4, 50> <<<1024, 256, 0, stream>>>(q1c, q2c, char_emb, w4, b4, buf0, xb16a);
    conv_kernel<5, 100><<<1024, 256, 0, stream>>>(q1c, q2c, char_emb, w5, b5, buf0, xb16a);
    wconv_kernel<<<(512 * DP + 255) / 256, 256, 0, stream>>>(hw_w, Wb16);

    // 2. highway x2 via MFMA
    dim3 hgrid(8, (2 * NT) / 64);
    highway_mfma_kernel<true> <<<hgrid, 256, 0, stream>>>(xb16a, buf0, Wb16, hw_b, buf1, xb16b);
    highway_mfma_kernel<false><<<hgrid, 256, 0, stream>>>(xb16b, buf1, Wb16, hw_b, buf0, nullptr);

    // 3. attn layer 0: x0 = buf0 -> x1 = buf1 (residual fused)
    attn_score_kernel<<<dim3(4, NBH), 256, 0, stream>>>(
        buf0, q1_len, q2_len, attn_w, attn_b, 0, A_g);
    attn_av_kernel<<<dim3(8, NBH), 256, 0, stream>>>(buf0, A_g, 1, buf1);

    // 4. attn layer 1: x1 = buf1 -> att -> d_out
    attn_score_kernel<<<dim3(4, NBH), 256, 0, stream>>>(
        buf1, q1_len, q2_len, attn_w, attn_b, 1, A_g);
    attn_av_kernel<<<dim3(8, NBH), 256, 0, stream>>>(buf1, A_g, 0, out);
}

// Round 7
// 465.762 us; speedup vs baseline: 2.5398x; 1.3126x over previous
//
#include <hip/hip_runtime.h>
#include <math.h>

// ---- problem constants ----
#define B   64
#define L   64
#define C   16
#define CHD 64
#define EMB 300
#define D   450       // EMB + 3*50
#define DP  480       // padded bf16 row stride
#define NT  (B*L)     // 4096 tokens per branch
#define NBH 128       // 2 branches * 64 batch

typedef short bf16x8 __attribute__((ext_vector_type(8)));
typedef float f32x4  __attribute__((ext_vector_type(4)));
typedef unsigned short ushort_t;

// ---------------- helpers ----------------
__device__ inline float wave_sum(float v) {
#pragma unroll
    for (int o = 32; o; o >>= 1) v += __shfl_xor(v, o, 64);
    return v;
}
__device__ inline float wave_max(float v) {
#pragma unroll
    for (int o = 32; o; o >>= 1) v = fmaxf(v, __shfl_xor(v, o, 64));
    return v;
}
__device__ inline ushort_t f2b(float f) {   // RNE float->bf16
    union { float f; unsigned u; } c; c.f = f;
    unsigned r = c.u + 0x7FFFu + ((c.u >> 16) & 1u);
    return (ushort_t)(r >> 16);
}

// ---------------- kernel 0: word embedding copy (f32 + bf16, zero-pad tail) ----------------
__global__ __launch_bounds__(256) void wordcopy_kernel(
    const int* __restrict__ q1, const int* __restrict__ q2,
    const float* __restrict__ word_emb, float* __restrict__ xout,
    ushort_t* __restrict__ xb16)
{
    const int tid = threadIdx.x;
#pragma unroll
    for (int t = 0; t < 4; ++t) {
        const int tok    = blockIdx.x * 4 + t;
        const int branch = tok >> 12;
        const int tokl   = tok & (NT - 1);
        const int w      = (branch ? q2 : q1)[tokl];
        const float* src = word_emb + (size_t)w * EMB;
        float*     dst   = xout + (size_t)tok * D;
        ushort_t*  dstb  = xb16 + (size_t)tok * DP;
        for (int d = tid; d < EMB; d += 256) {
            float v = src[d];
            dst[d] = v;
            dstb[d] = f2b(v);
        }
        if (tid < DP - D) dstb[D + tid] = 0;
    }
}

// ---------------- prep: Wpad bf16 [160][320] (K-major, zero-padded), bias160, char_emb bf16 ----------------
__global__ __launch_bounds__(256) void conv_prep_kernel(
    const float* __restrict__ w3, const float* __restrict__ b3,
    const float* __restrict__ w4, const float* __restrict__ b4,
    const float* __restrict__ w5, const float* __restrict__ b5,
    const float* __restrict__ char_emb,
    ushort_t* __restrict__ Wpad, float* __restrict__ bias160,
    ushort_t* __restrict__ ceb16)
{
    int idx = blockIdx.x * 256 + threadIdx.x;
    if (idx < 160 * 320) {
        int f = idx / 320, kd = idx - f * 320;
        int k = kd >> 6, d = kd & 63;
        float v = 0.f;
        if (f < 50)       { if (k < 3) v = w3[f * 192 + d * 3 + k]; }
        else if (f < 100) { if (k < 4) v = w4[(f - 50) * 256 + d * 4 + k]; }
        else if (f < 150) { v = w5[(f - 100) * 320 + d * 5 + k]; }
        Wpad[idx] = f2b(v);
    } else if (idx < 160 * 320 + 160) {
        int f = idx - 160 * 320;
        bias160[f] = (f < 50) ? b3[f] : (f < 100) ? b4[f - 50] : (f < 150) ? b5[f - 100] : 0.f;
    } else if (idx < 160 * 320 + 160 + 100 * 64) {
        int i = idx - (160 * 320 + 160);
        ceb16[i] = f2b(char_emb[i]);
    }
}

// ---------------- kernel 1: unified char conv via bf16 MFMA ----------------
// block = 256 (4 waves), 32 tokens/block (4 rounds x 8), grid 256.
// GEMM per token: H[16 pos][160 filt] = A[16][320] x Wpad[160][320]^T, then masked maxpool.
#define WPS 328            // Wpad LDS row stride (ushorts): 164 dwords % 32 = 4 -> 2-way
#define ESS 72             // e_pad row stride (ushorts): 36 dwords % 32 = 4 -> 2-way
#define EST (20 * ESS)     // per-token e_pad size (20 rows)

__global__ __launch_bounds__(256) void conv_mfma_kernel(
    const int* __restrict__ q1c, const int* __restrict__ q2c,
    const ushort_t* __restrict__ ceb16,
    const ushort_t* __restrict__ Wpad, const float* __restrict__ bias160,
    float* __restrict__ xout, ushort_t* __restrict__ xb16)
{
    __shared__ ushort_t Wl[160 * WPS];   // 104960 B
    __shared__ ushort_t es[8 * EST];     // 23040 B

    const int tid  = threadIdx.x;
    const int wv   = tid >> 6;
    const int lane = tid & 63;
    const int ln   = lane & 15, quad = lane >> 4;
    const int tokbase = blockIdx.x * 32;

    // stage Wpad into LDS (16B chunks; rows padded to WPS)
    for (int c = tid; c < 160 * 40; c += 256) {
        int f = c / 40, part = c - f * 40;
        *(bf16x8*)&Wl[f * WPS + part * 8] = *(const bf16x8*)&Wpad[f * 320 + part * 8];
    }

#pragma unroll 1
    for (int round = 0; round < 4; ++round) {
        __syncthreads();   // Wl ready (round 0) + WAR on es
        // ---- stage e_pad for 8 tokens: 128 char-rows x 64 bf16 (8 chunks each) ----
#pragma unroll
        for (int i = 0; i < 4; ++i) {
            int c = tid + i * 256;          // 0..1023
            int row = c >> 3, part = c & 7;
            int tl = row >> 4, cr = row & 15;
            int gtok   = tokbase + round * 8 + tl;
            int branch = gtok >> 12;
            int tokl   = gtok & (NT - 1);
            int cid    = (branch ? q2c : q1c)[tokl * C + cr];
            *(bf16x8*)&es[tl * EST + cr * ESS + part * 8] =
                *(const bf16x8*)&ceb16[cid * 64 + part * 8];
        }
        // zero rows 16..19
        {
            int c = tid;                    // 0..255 exactly covers 8*4*8 chunks
            int tl = c >> 5, rr = (c >> 3) & 3, part = c & 7;
            bf16x8 z = {0, 0, 0, 0, 0, 0, 0, 0};
            *(bf16x8*)&es[tl * EST + (16 + rr) * ESS + part * 8] = z;
        }
        __syncthreads();

        // ---- compute: each wave does 2 tokens ----
        const int t0 = wv * 2, t1 = t0 + 1;
        f32x4 acc[2][10];
#pragma unroll
        for (int t = 0; t < 2; ++t)
#pragma unroll
            for (int nt = 0; nt < 10; ++nt) acc[t][nt] = (f32x4){0.f, 0.f, 0.f, 0.f};

#pragma unroll 1
        for (int ks = 0; ks < 10; ++ks) {
            const int kk   = ks * 32 + quad * 8;
            const int arow = kk >> 6, aoff = kk & 63;
            bf16x8 a0 = *(const bf16x8*)&es[t0 * EST + (ln + arow) * ESS + aoff];
            bf16x8 a1 = *(const bf16x8*)&es[t1 * EST + (ln + arow) * ESS + aoff];
#pragma unroll
            for (int nt = 0; nt < 10; ++nt) {
                bf16x8 bf = *(const bf16x8*)&Wl[(nt * 16 + ln) * WPS + kk];
                acc[0][nt] = __builtin_amdgcn_mfma_f32_16x16x32_bf16(a0, bf, acc[0][nt], 0, 0, 0);
                acc[1][nt] = __builtin_amdgcn_mfma_f32_16x16x32_bf16(a1, bf, acc[1][nt], 0, 0, 0);
            }
        }

        // ---- epilogue: masked max over positions, relu(max+b), write ----
#pragma unroll
        for (int t = 0; t < 2; ++t) {
            const int gtok = tokbase + round * 8 + t0 + t;
#pragma unroll
            for (int nt = 0; nt < 10; ++nt) {
                const int f  = nt * 16 + ln;              // C/D: col = lane&15 -> filter
                const int Pf = (f < 50) ? 14 : (f < 100) ? 13 : 12;
                float m = -1e30f;
#pragma unroll
                for (int r = 0; r < 4; ++r) {             // row = quad*4 + r -> position
                    const int p = quad * 4 + r;
                    if (p < Pf) m = fmaxf(m, acc[t][nt][r]);
                }
                m = fmaxf(m, __shfl_xor(m, 16, 64));
                m = fmaxf(m, __shfl_xor(m, 32, 64));
                if (quad == 0 && f < 150) {
                    float rv = fmaxf(0.f, m + bias160[f]);
                    xout[(size_t)gtok * D + EMB + f] = rv;
                    xb16[(size_t)gtok * DP + EMB + f] = f2b(rv);
                }
            }
        }
    }
}

// ---------------- kernel 1b: highway W -> bf16 padded image (512 x 480) ----------------
__global__ __launch_bounds__(256) void wconv_kernel(
    const float* __restrict__ W, ushort_t* __restrict__ Wb16)
{
    int idx = blockIdx.x * 256 + threadIdx.x;
    if (idx >= 512 * DP) return;
    int n = idx / DP, k = idx - n * DP;
    float v = (n < D && k < D) ? W[(size_t)n * D + k] : 0.f;
    Wb16[idx] = f2b(v);
}

// ---------------- kernel 2: highway via bf16 MFMA (no LDS) ----------------
template <bool EMIT>
__global__ __launch_bounds__(256) void highway_mfma_kernel(
    const ushort_t* __restrict__ xb16, const float* __restrict__ xf32,
    const ushort_t* __restrict__ Wb16, const float* __restrict__ bvec,
    float* __restrict__ out, ushort_t* __restrict__ outb16)
{
    const int tid  = threadIdx.x;
    const int wv   = tid >> 6;
    const int lane = tid & 63;
    const int wm = wv >> 1, wn = wv & 1;
    const int m0 = blockIdx.y * 64 + wm * 32;
    const int n0 = blockIdx.x * 64 + wn * 32;
    const int lm = lane & 15, quad = lane >> 4;

    const ushort_t* ax = xb16 + (size_t)(m0 + lm) * DP + quad * 8;
    const ushort_t* bw = Wb16 + (size_t)(n0 + lm) * DP + quad * 8;

    f32x4 acc[2][2];
#pragma unroll
    for (int i = 0; i < 2; ++i)
#pragma unroll
        for (int j = 0; j < 2; ++j) acc[i][j] = (f32x4){0.f, 0.f, 0.f, 0.f};

#pragma unroll 1
    for (int k0 = 0; k0 < DP; k0 += 32) {
        bf16x8 a0 = *(const bf16x8*)(ax + k0);
        bf16x8 a1 = *(const bf16x8*)(ax + (size_t)16 * DP + k0);
        bf16x8 b0 = *(const bf16x8*)(bw + k0);
        bf16x8 b1 = *(const bf16x8*)(bw + (size_t)16 * DP + k0);
        acc[0][0] = __builtin_amdgcn_mfma_f32_16x16x32_bf16(a0, b0, acc[0][0], 0, 0, 0);
        acc[0][1] = __builtin_amdgcn_mfma_f32_16x16x32_bf16(a0, b1, acc[0][1], 0, 0, 0);
        acc[1][0] = __builtin_amdgcn_mfma_f32_16x16x32_bf16(a1, b0, acc[1][0], 0, 0, 0);
        acc[1][1] = __builtin_amdgcn_mfma_f32_16x16x32_bf16(a1, b1, acc[1][1], 0, 0, 0);
    }

#pragma unroll
    for (int nt = 0; nt < 2; ++nt) {
        const int n = n0 + nt * 16 + lm;
        const bool nval = (n < D);
        const float bv = nval ? bvec[n] : 0.f;
#pragma unroll
        for (int mt = 0; mt < 2; ++mt) {
#pragma unroll
            for (int r = 0; r < 4; ++r) {
                const int m = m0 + mt * 16 + quad * 4 + r;
                float y = acc[mt][nt][r] + bv;
                float g = 1.f / (1.f + __expf(-y));
                float o = 0.f;
                if (nval) {
                    float xo = xf32[(size_t)m * D + n];
                    o = g * fmaxf(y, 0.f) + (1.f - g) * xo;
                    out[(size_t)m * D + n] = o;
                }
                if (EMIT && n < DP)
                    outb16[(size_t)m * DP + n] = f2b(nval ? o : 0.f);
            }
        }
    }
}

// ---------------- kernel 3b: scores + softmax -> A (s1/s2 fused in) ----------------
#define APAD 68

__global__ __launch_bounds__(256, 4) void attn_score_kernel(
    const float* __restrict__ x,
    const int* __restrict__ q1_len, const int* __restrict__ q2_len,
    const float* __restrict__ attn_w, const float* __restrict__ attn_b,
    int layer, float* __restrict__ A_g)
{
    const int it = blockIdx.x, bh = blockIdx.y;
    const int i0 = it * 16;
    const int branch = bh >> 6, b = bh & 63;
    const int tid = threadIdx.x;
    const int tj = tid & 15, ti = tid >> 4;
    const int wv_  = tid >> 6;
    const int lane = tid & 63;

    const float* xb  = x + (size_t)bh * L * D;
    const float* wb  = attn_w + (size_t)layer * 3 * D;   // w1 | w2 | w3
    const float* w3g = wb + 2 * D;

    __shared__ float As[32][17];
    __shared__ float Bs[32][APAD];
    __shared__ float Ssh[16][65];
    __shared__ float s1s[16], s2s[64];

#pragma unroll 1
    for (int p = wv_; p < 80; p += 4) {
        const int    row  = (p < 16) ? (i0 + p) : (p - 16);
        const float* wsel = (p < 16) ? wb : (wb + D);
        const float* xr   = xb + (size_t)row * D;
        float s = 0.f;
#pragma unroll
        for (int t = 0; t < 8; ++t) {
            int k = lane + t * 64;
            if (k < D) s = fmaf(xr[k], wsel[k], s);
        }
        s = wave_sum(s);
        if (lane == 0) { if (p < 16) s1s[p] = s; else s2s[p - 16] = s; }
    }

    float acc[4] = {};
#pragma unroll 1
    for (int k0 = 0; k0 < D; k0 += 32) {
        __syncthreads();
#pragma unroll
        for (int u = 0; u < 2; ++u) {
            int idx = tid + u * 256;
            int k = idx & 31, i = idx >> 5;
            int gk = k0 + k;
            As[k][i] = (gk < D) ? xb[(size_t)(i0 + i) * D + gk] : 0.f;
        }
#pragma unroll
        for (int u = 0; u < 8; ++u) {
            int idx = tid + u * 256;
            int k = idx & 31, j = idx >> 5;
            int gk = k0 + k;
            Bs[k][j] = (gk < D) ? xb[(size_t)j * D + gk] * w3g[gk] : 0.f;
        }
        __syncthreads();
#pragma unroll 8
        for (int kk = 0; kk < 32; ++kk) {
            float a = As[kk][ti];
            float4 bq = *(const float4*)&Bs[kk][tj * 4];
            acc[0] = fmaf(a, bq.x, acc[0]);
            acc[1] = fmaf(a, bq.y, acc[1]);
            acc[2] = fmaf(a, bq.z, acc[2]);
            acc[3] = fmaf(a, bq.w, acc[3]);
        }
    }
#pragma unroll
    for (int q = 0; q < 4; ++q) Ssh[ti][tj * 4 + q] = acc[q];
    __syncthreads();

    const int   len  = (branch ? q2_len : q1_len)[b];
    const float bias = attn_b[layer];

    const int j  = tid & 63;
    const int rq = tid >> 6;
    const float s2v = s2s[j];
#pragma unroll
    for (int rr = 0; rr < 4; ++rr) {
        const int r = rq * 4 + rr;
        float s = Ssh[r][j] + s1s[r] + s2v + bias;
        if (j >= len) s = -1e-9f;            // reference's (buggy) mask value
        const float mx = wave_max(s);
        const float ev = __expf(s - mx);
        const float sm = wave_sum(ev);
        A_g[(size_t)bh * (L * L) + (size_t)(i0 + r) * L + j] = ev / sm;
    }
}

// ---------------- kernel 3c: out = A @ X (+ residual) ----------------
__global__ __launch_bounds__(256, 4) void attn_av_kernel(
    const float* __restrict__ x, const float* __restrict__ A_g,
    int add_resid, float* __restrict__ out)
{
    const int dt = blockIdx.x, bh = blockIdx.y;
    const int d0 = dt * 64;
    const int tid = threadIdx.x;
    const int td = tid & 15, ti = tid >> 4;
    const int d4 = td * 4, i4 = ti * 4;

    const float* xb = x + (size_t)bh * L * D;
    const float* Ab = A_g + (size_t)bh * (L * L);

    __shared__ float Ash[L][APAD];   // [k=j][i]
    __shared__ float Xc[L][APAD];    // [k=j][d]

    for (int idx = tid; idx < L * L; idx += 256) {
        int j = idx & 63, i = idx >> 6;
        Ash[j][i] = Ab[(size_t)i * L + j];
    }
    for (int idx = tid; idx < L * 64; idx += 256) {
        int d = idx & 63, j = idx >> 6;
        int gd = d0 + d;
        Xc[j][d] = (gd < D) ? xb[(size_t)j * D + gd] : 0.f;
    }
    __syncthreads();

    float acc[4][4] = {};
#pragma unroll 8
    for (int k = 0; k < L; ++k) {
        float4 av = *(const float4*)&Ash[k][i4];
        float4 xv = *(const float4*)&Xc[k][d4];
        const float a[4] = {av.x, av.y, av.z, av.w};
        const float xr[4] = {xv.x, xv.y, xv.z, xv.w};
#pragma unroll
        for (int i = 0; i < 4; ++i)
#pragma unroll
            for (int d = 0; d < 4; ++d) acc[i][d] = fmaf(a[i], xr[d], acc[i][d]);
    }

    float* ob = out + (size_t)bh * L * D;
#pragma unroll
    for (int i = 0; i < 4; ++i) {
        const int gi = i4 + i;
#pragma unroll
        for (int d = 0; d < 4; ++d) {
            const int gd = d0 + d4 + d;
            if (gd < D) {
                float v = acc[i][d];
                if (add_resid) v += Xc[gi][d4 + d];
                ob[(size_t)gi * D + gd] = v;
            }
        }
    }
}

// ---------------- launch ----------------
extern "C" void kernel_launch(void* const* d_in, const int* in_sizes, int n_in,
                              void* d_out, int out_size, void* d_ws, size_t ws_size,
                              hipStream_t stream) {
    const int*   q1       = (const int*)  d_in[0];
    const int*   q2       = (const int*)  d_in[1];
    const int*   q1_len   = (const int*)  d_in[2];
    const int*   q2_len   = (const int*)  d_in[3];
    const int*   q1c      = (const int*)  d_in[4];
    const int*   q2c      = (const int*)  d_in[5];
    const float* word_emb = (const float*)d_in[6];
    const float* char_emb = (const float*)d_in[7];
    const float* w3       = (const float*)d_in[8];
    const float* b3       = (const float*)d_in[9];
    const float* w4       = (const float*)d_in[10];
    const float* b4       = (const float*)d_in[11];
    const float* w5       = (const float*)d_in[12];
    const float* b5       = (const float*)d_in[13];
    const float* hw_w     = (const float*)d_in[14];
    const float* hw_b     = (const float*)d_in[15];
    const float* attn_w   = (const float*)d_in[16];
    const float* attn_b   = (const float*)d_in[17];
    float* out = (float*)d_out;

    float*    buf0    = (float*)d_ws;                          // 2*NT*D f32
    float*    buf1    = buf0 + (size_t)2 * NT * D;             // 2*NT*D f32
    float*    A_g     = buf1 + (size_t)2 * NT * D;             // NBH*L*L f32
    float*    bias160 = A_g + (size_t)NBH * L * L;             // 160 f32
    ushort_t* xb16a   = (ushort_t*)(bias160 + 160);            // 2*NT*DP bf16
    ushort_t* xb16b   = xb16a + (size_t)2 * NT * DP;           // 2*NT*DP bf16
    ushort_t* Wb16    = xb16b + (size_t)2 * NT * DP;           // 512*DP bf16
    ushort_t* Wpad    = Wb16 + (size_t)512 * DP;               // 160*320 bf16
    ushort_t* ceb16   = Wpad + (size_t)160 * 320;              // 100*64 bf16

    // 1. prep + embeddings + conv
    conv_prep_kernel<<<226, 256, 0, stream>>>(w3, b3, w4, b4, w5, b5, char_emb,
                                              Wpad, bias160, ceb16);
    wconv_kernel<<<(512 * DP + 255) / 256, 256, 0, stream>>>(hw_w, Wb16);
    wordcopy_kernel<<<2 * NT / 4, 256, 0, stream>>>(q1, q2, word_emb, buf0, xb16a);
    conv_mfma_kernel<<<256, 256, 0, stream>>>(q1c, q2c, ceb16, Wpad, bias160, buf0, xb16a);

    // 2. highway x2 via MFMA
    dim3 hgrid(8, (2 * NT) / 64);
    highway_mfma_kernel<true> <<<hgrid, 256, 0, stream>>>(xb16a, buf0, Wb16, hw_b, buf1, xb16b);
    highway_mfma_kernel<false><<<hgrid, 256, 0, stream>>>(xb16b, buf1, Wb16, hw_b, buf0, nullptr);

    // 3. attn layer 0: x0 = buf0 -> x1 = buf1 (residual fused)
    attn_score_kernel<<<dim3(4, NBH), 256, 0, stream>>>(
        buf0, q1_len, q2_len, attn_w, attn_b, 0, A_g);
    attn_av_kernel<<<dim3(8, NBH), 256, 0, stream>>>(buf0, A_g, 1, buf1);

    // 4. attn layer 1: x1 = buf1 -> att -> d_out
    attn_score_kernel<<<dim3(4, NBH), 256, 0, stream>>>(
        buf1, q1_len, q2_len, attn_w, attn_b, 1, A_g);
    attn_av_kernel<<<dim3(8, NBH), 256, 0, stream>>>(buf1, A_g, 0, out);
}

// Round 8
// 428.601 us; speedup vs baseline: 2.7600x; 1.0867x over previous
//
#include <hip/hip_runtime.h>
#include <math.h>

// ---- problem constants ----
#define B   64
#define L   64
#define C   16
#define CHD 64
#define EMB 300
#define D   450       // EMB + 3*50
#define DP  480       // padded bf16 row stride
#define NT  (B*L)     // 4096 tokens per branch
#define NBH 128       // 2 branches * 64 batch

typedef short bf16x8 __attribute__((ext_vector_type(8)));
typedef float f32x4  __attribute__((ext_vector_type(4)));
typedef unsigned short ushort_t;

// ---------------- helpers ----------------
__device__ inline float wave_sum(float v) {
#pragma unroll
    for (int o = 32; o; o >>= 1) v += __shfl_xor(v, o, 64);
    return v;
}
__device__ inline ushort_t f2b(float f) {   // RNE float->bf16
    union { float f; unsigned u; } c; c.f = f;
    unsigned r = c.u + 0x7FFFu + ((c.u >> 16) & 1u);
    return (ushort_t)(r >> 16);
}

// ---------------- kernel 0: word embedding copy (f32 + bf16, zero-pad tail) ----------------
__global__ __launch_bounds__(256) void wordcopy_kernel(
    const int* __restrict__ q1, const int* __restrict__ q2,
    const float* __restrict__ word_emb, float* __restrict__ xout,
    ushort_t* __restrict__ xb16)
{
    const int tid = threadIdx.x;
#pragma unroll
    for (int t = 0; t < 4; ++t) {
        const int tok    = blockIdx.x * 4 + t;
        const int branch = tok >> 12;
        const int tokl   = tok & (NT - 1);
        const int w      = (branch ? q2 : q1)[tokl];
        const float* src = word_emb + (size_t)w * EMB;
        float*     dst   = xout + (size_t)tok * D;
        ushort_t*  dstb  = xb16 + (size_t)tok * DP;
        for (int d = tid; d < EMB; d += 256) {
            float v = src[d];
            dst[d] = v;
            dstb[d] = f2b(v);
        }
        if (tid < DP - D) dstb[D + tid] = 0;
    }
}

// ---------------- prep: Wpad bf16 [160][320], bias160, char_emb bf16 ----------------
__global__ __launch_bounds__(256) void conv_prep_kernel(
    const float* __restrict__ w3, const float* __restrict__ b3,
    const float* __restrict__ w4, const float* __restrict__ b4,
    const float* __restrict__ w5, const float* __restrict__ b5,
    const float* __restrict__ char_emb,
    ushort_t* __restrict__ Wpad, float* __restrict__ bias160,
    ushort_t* __restrict__ ceb16)
{
    int idx = blockIdx.x * 256 + threadIdx.x;
    if (idx < 160 * 320) {
        int f = idx / 320, kd = idx - f * 320;
        int k = kd >> 6, d = kd & 63;
        float v = 0.f;
        if (f < 50)       { if (k < 3) v = w3[f * 192 + d * 3 + k]; }
        else if (f < 100) { if (k < 4) v = w4[(f - 50) * 256 + d * 4 + k]; }
        else if (f < 150) { v = w5[(f - 100) * 320 + d * 5 + k]; }
        Wpad[idx] = f2b(v);
    } else if (idx < 160 * 320 + 160) {
        int f = idx - 160 * 320;
        bias160[f] = (f < 50) ? b3[f] : (f < 100) ? b4[f - 50] : (f < 150) ? b5[f - 100] : 0.f;
    } else if (idx < 160 * 320 + 160 + 100 * 64) {
        int i = idx - (160 * 320 + 160);
        ceb16[i] = f2b(char_emb[i]);
    }
}

// ---------------- kernel 1: unified char conv via bf16 MFMA ----------------
#define WPS 328
#define ESS 72
#define EST (20 * ESS)

__global__ __launch_bounds__(256) void conv_mfma_kernel(
    const int* __restrict__ q1c, const int* __restrict__ q2c,
    const ushort_t* __restrict__ ceb16,
    const ushort_t* __restrict__ Wpad, const float* __restrict__ bias160,
    float* __restrict__ xout, ushort_t* __restrict__ xb16)
{
    __shared__ ushort_t Wl[160 * WPS];
    __shared__ ushort_t es[8 * EST];

    const int tid  = threadIdx.x;
    const int wv   = tid >> 6;
    const int lane = tid & 63;
    const int ln   = lane & 15, quad = lane >> 4;
    const int tokbase = blockIdx.x * 32;

    for (int c = tid; c < 160 * 40; c += 256) {
        int f = c / 40, part = c - f * 40;
        *(bf16x8*)&Wl[f * WPS + part * 8] = *(const bf16x8*)&Wpad[f * 320 + part * 8];
    }

#pragma unroll 1
    for (int round = 0; round < 4; ++round) {
        __syncthreads();
#pragma unroll
        for (int i = 0; i < 4; ++i) {
            int c = tid + i * 256;
            int row = c >> 3, part = c & 7;
            int tl = row >> 4, cr = row & 15;
            int gtok   = tokbase + round * 8 + tl;
            int branch = gtok >> 12;
            int tokl   = gtok & (NT - 1);
            int cid    = (branch ? q2c : q1c)[tokl * C + cr];
            *(bf16x8*)&es[tl * EST + cr * ESS + part * 8] =
                *(const bf16x8*)&ceb16[cid * 64 + part * 8];
        }
        {
            int c = tid;
            int tl = c >> 5, rr = (c >> 3) & 3, part = c & 7;
            bf16x8 z = {0, 0, 0, 0, 0, 0, 0, 0};
            *(bf16x8*)&es[tl * EST + (16 + rr) * ESS + part * 8] = z;
        }
        __syncthreads();

        const int t0 = wv * 2, t1 = t0 + 1;
        f32x4 acc[2][10];
#pragma unroll
        for (int t = 0; t < 2; ++t)
#pragma unroll
            for (int nt = 0; nt < 10; ++nt) acc[t][nt] = (f32x4){0.f, 0.f, 0.f, 0.f};

#pragma unroll 1
        for (int ks = 0; ks < 10; ++ks) {
            const int kk   = ks * 32 + quad * 8;
            const int arow = kk >> 6, aoff = kk & 63;
            bf16x8 a0 = *(const bf16x8*)&es[t0 * EST + (ln + arow) * ESS + aoff];
            bf16x8 a1 = *(const bf16x8*)&es[t1 * EST + (ln + arow) * ESS + aoff];
#pragma unroll
            for (int nt = 0; nt < 10; ++nt) {
                bf16x8 bf = *(const bf16x8*)&Wl[(nt * 16 + ln) * WPS + kk];
                acc[0][nt] = __builtin_amdgcn_mfma_f32_16x16x32_bf16(a0, bf, acc[0][nt], 0, 0, 0);
                acc[1][nt] = __builtin_amdgcn_mfma_f32_16x16x32_bf16(a1, bf, acc[1][nt], 0, 0, 0);
            }
        }

#pragma unroll
        for (int t = 0; t < 2; ++t) {
            const int gtok = tokbase + round * 8 + t0 + t;
#pragma unroll
            for (int nt = 0; nt < 10; ++nt) {
                const int f  = nt * 16 + ln;
                const int Pf = (f < 50) ? 14 : (f < 100) ? 13 : 12;
                float m = -1e30f;
#pragma unroll
                for (int r = 0; r < 4; ++r) {
                    const int p = quad * 4 + r;
                    if (p < Pf) m = fmaxf(m, acc[t][nt][r]);
                }
                m = fmaxf(m, __shfl_xor(m, 16, 64));
                m = fmaxf(m, __shfl_xor(m, 32, 64));
                if (quad == 0 && f < 150) {
                    float rv = fmaxf(0.f, m + bias160[f]);
                    xout[(size_t)gtok * D + EMB + f] = rv;
                    xb16[(size_t)gtok * DP + EMB + f] = f2b(rv);
                }
            }
        }
    }
}

// ---------------- kernel 1b: highway W -> bf16 padded image ----------------
__global__ __launch_bounds__(256) void wconv_kernel(
    const float* __restrict__ W, ushort_t* __restrict__ Wb16)
{
    int idx = blockIdx.x * 256 + threadIdx.x;
    if (idx >= 512 * DP) return;
    int n = idx / DP, k = idx - n * DP;
    float v = (n < D && k < D) ? W[(size_t)n * D + k] : 0.f;
    Wb16[idx] = f2b(v);
}

// ---------------- kernel 2: highway via bf16 MFMA (no LDS) ----------------
__global__ __launch_bounds__(256) void highway_mfma_kernel(
    const ushort_t* __restrict__ xb16, const float* __restrict__ xf32,
    const ushort_t* __restrict__ Wb16, const float* __restrict__ bvec,
    float* __restrict__ out, ushort_t* __restrict__ outb16)
{
    const int tid  = threadIdx.x;
    const int wv   = tid >> 6;
    const int lane = tid & 63;
    const int wm = wv >> 1, wn = wv & 1;
    const int m0 = blockIdx.y * 64 + wm * 32;
    const int n0 = blockIdx.x * 64 + wn * 32;
    const int lm = lane & 15, quad = lane >> 4;

    const ushort_t* ax = xb16 + (size_t)(m0 + lm) * DP + quad * 8;
    const ushort_t* bw = Wb16 + (size_t)(n0 + lm) * DP + quad * 8;

    f32x4 acc[2][2];
#pragma unroll
    for (int i = 0; i < 2; ++i)
#pragma unroll
        for (int j = 0; j < 2; ++j) acc[i][j] = (f32x4){0.f, 0.f, 0.f, 0.f};

#pragma unroll 1
    for (int k0 = 0; k0 < DP; k0 += 32) {
        bf16x8 a0 = *(const bf16x8*)(ax + k0);
        bf16x8 a1 = *(const bf16x8*)(ax + (size_t)16 * DP + k0);
        bf16x8 b0 = *(const bf16x8*)(bw + k0);
        bf16x8 b1 = *(const bf16x8*)(bw + (size_t)16 * DP + k0);
        acc[0][0] = __builtin_amdgcn_mfma_f32_16x16x32_bf16(a0, b0, acc[0][0], 0, 0, 0);
        acc[0][1] = __builtin_amdgcn_mfma_f32_16x16x32_bf16(a0, b1, acc[0][1], 0, 0, 0);
        acc[1][0] = __builtin_amdgcn_mfma_f32_16x16x32_bf16(a1, b0, acc[1][0], 0, 0, 0);
        acc[1][1] = __builtin_amdgcn_mfma_f32_16x16x32_bf16(a1, b1, acc[1][1], 0, 0, 0);
    }

#pragma unroll
    for (int nt = 0; nt < 2; ++nt) {
        const int n = n0 + nt * 16 + lm;
        const bool nval = (n < D);
        const float bv = nval ? bvec[n] : 0.f;
#pragma unroll
        for (int mt = 0; mt < 2; ++mt) {
#pragma unroll
            for (int r = 0; r < 4; ++r) {
                const int m = m0 + mt * 16 + quad * 4 + r;
                float y = acc[mt][nt][r] + bv;
                float g = 1.f / (1.f + __expf(-y));
                float o = 0.f;
                if (nval) {
                    float xo = xf32[(size_t)m * D + n];
                    o = g * fmaxf(y, 0.f) + (1.f - g) * xo;
                    out[(size_t)m * D + n] = o;
                }
                if (n < DP)
                    outb16[(size_t)m * DP + n] = f2b(nval ? o : 0.f);
            }
        }
    }
}

// ---------------- kernel 3: fused self-attention via bf16 MFMA ----------------
// one block per bh; 256 threads (4 waves); everything in LDS.
#define XWS 488   // Xw3 LDS row stride (bf16)
#define XTS 72    // X^T LDS row stride (bf16)
#define ALS 72    // P (A) LDS row stride (bf16)

template <bool RES_EMIT>
__global__ __launch_bounds__(256) void attn_fused_kernel(
    const float* __restrict__ xf32, const ushort_t* __restrict__ xb16,
    const int* __restrict__ q1_len, const int* __restrict__ q2_len,
    const float* __restrict__ attn_w, const float* __restrict__ attn_b,
    int layer, float* __restrict__ outf, ushort_t* __restrict__ outb16)
{
    __shared__ ushort_t Xw3[64 * XWS];   // 62464 B
    __shared__ ushort_t XT[DP * XTS];    // 69120 B
    __shared__ ushort_t Al[64 * ALS];    // 9216 B
    __shared__ float s1s[64], s2s[64];

    const int bh     = blockIdx.x;
    const int branch = bh >> 6, b = bh & 63;
    const int tid  = threadIdx.x;
    const int wv   = tid >> 6;
    const int lane = tid & 63;
    const int ln   = lane & 15, quad = lane >> 4;

    const float*    xfb = xf32 + (size_t)bh * L * D;
    const ushort_t* xbb = xb16 + (size_t)bh * L * DP;
    const float*    wb  = attn_w + (size_t)layer * 3 * D;   // w1 | w2 | w3
    const float*    w3g = wb + 2 * D;

    // ---- stage Xw3 = f2b(x * w3), row-major [j][k] ----
    {
        const int j = tid >> 2, kc = tid & 3;
        const float* xr = xfb + (size_t)j * D;
#pragma unroll 1
        for (int kk = 0; kk < 15; ++kk) {
            const int k0 = kc * 120 + kk * 8;
            bf16x8 pk;
#pragma unroll
            for (int t = 0; t < 8; ++t) {
                const int k = k0 + t;
                float v = (k < D) ? xr[k] * w3g[k] : 0.f;
                pk[t] = (short)f2b(v);
            }
            *(bf16x8*)&Xw3[j * XWS + k0] = pk;
        }
    }
    // ---- stage X^T [d][j] from bf16 mirror ----
#pragma unroll 1
    for (int c = tid; c < 64 * 60; c += 256) {
        const int j = c & 63, dc = c >> 6;
        bf16x8 v = *(const bf16x8*)&xbb[(size_t)j * DP + dc * 8];
#pragma unroll
        for (int t = 0; t < 8; ++t)
            XT[(dc * 8 + t) * XTS + j] = (ushort_t)v[t];
    }
    // ---- s1[i] = x_i.w1, s2[j] = x_j.w2 (f32 VALU) ----
#pragma unroll 1
    for (int p = wv; p < 128; p += 4) {
        const int row = p & 63;
        const float* wsel = (p < 64) ? wb : (wb + D);
        const float* xr = xfb + (size_t)row * D;
        float s = 0.f;
#pragma unroll
        for (int t = 0; t < 8; ++t) {
            int k = lane + t * 64;
            if (k < D) s = fmaf(xr[k], wsel[k], s);
        }
        s = wave_sum(s);
        if (lane == 0) { if (p < 64) s1s[row] = s; else s2s[row] = s; }
    }
    __syncthreads();

    // ---- QK^T: wave wv computes rows i0..i0+15 x all 64 j ----
    const int i0 = wv * 16;
    const ushort_t* ap = xbb + (size_t)(i0 + ln) * DP + quad * 8;
    f32x4 qacc[4];
#pragma unroll
    for (int jt = 0; jt < 4; ++jt) qacc[jt] = (f32x4){0.f, 0.f, 0.f, 0.f};
#pragma unroll 1
    for (int ks = 0; ks < 15; ++ks) {
        bf16x8 a = *(const bf16x8*)(ap + ks * 32);
#pragma unroll
        for (int jt = 0; jt < 4; ++jt) {
            bf16x8 bq = *(const bf16x8*)&Xw3[(jt * 16 + ln) * XWS + quad * 8 + ks * 32];
            qacc[jt] = __builtin_amdgcn_mfma_f32_16x16x32_bf16(a, bq, qacc[jt], 0, 0, 0);
        }
    }

    // ---- softmax (in-register; row i = i0 + quad*4 + reg, col j = jt*16 + ln) ----
    const int   len  = (branch ? q2_len : q1_len)[b];
    const float bias = attn_b[layer];
#pragma unroll
    for (int reg = 0; reg < 4; ++reg) {
        const int i = i0 + quad * 4 + reg;
        float s[4];
#pragma unroll
        for (int jt = 0; jt < 4; ++jt) {
            const int j = jt * 16 + ln;
            float v = qacc[jt][reg] + s1s[i] + s2s[j] + bias;
            if (j >= len) v = -1e-9f;        // reference's (buggy) mask value
            s[jt] = v;
        }
        float m = fmaxf(fmaxf(s[0], s[1]), fmaxf(s[2], s[3]));
#pragma unroll
        for (int o = 1; o < 16; o <<= 1) m = fmaxf(m, __shfl_xor(m, o, 64));
        float ev[4], sm = 0.f;
#pragma unroll
        for (int jt = 0; jt < 4; ++jt) { ev[jt] = __expf(s[jt] - m); sm += ev[jt]; }
#pragma unroll
        for (int o = 1; o < 16; o <<= 1) sm += __shfl_xor(sm, o, 64);
        const float inv = 1.f / sm;
#pragma unroll
        for (int jt = 0; jt < 4; ++jt)
            Al[i * ALS + jt * 16 + ln] = f2b(ev[jt] * inv);
    }
    __syncthreads();

    // ---- AV: out[i][d] = sum_j A[i][j] X[j][d] (+ residual) ----
    bf16x8 af0 = *(const bf16x8*)&Al[(i0 + ln) * ALS + quad * 8];
    bf16x8 af1 = *(const bf16x8*)&Al[(i0 + ln) * ALS + quad * 8 + 32];
#pragma unroll 1
    for (int pass = 0; pass < 3; ++pass) {
        f32x4 acc[10];
#pragma unroll
        for (int t = 0; t < 10; ++t) acc[t] = (f32x4){0.f, 0.f, 0.f, 0.f};
#pragma unroll
        for (int t = 0; t < 10; ++t) {
            const int dt = pass * 10 + t;
            bf16x8 b0 = *(const bf16x8*)&XT[(dt * 16 + ln) * XTS + quad * 8];
            bf16x8 b1 = *(const bf16x8*)&XT[(dt * 16 + ln) * XTS + quad * 8 + 32];
            acc[t] = __builtin_amdgcn_mfma_f32_16x16x32_bf16(af0, b0, acc[t], 0, 0, 0);
            acc[t] = __builtin_amdgcn_mfma_f32_16x16x32_bf16(af1, b1, acc[t], 0, 0, 0);
        }
#pragma unroll
        for (int t = 0; t < 10; ++t) {
            const int d = (pass * 10 + t) * 16 + ln;
            if (d >= D) continue;
#pragma unroll
            for (int reg = 0; reg < 4; ++reg) {
                const int i = i0 + quad * 4 + reg;
                float v = acc[t][reg];
                if (RES_EMIT) v += xfb[(size_t)i * D + d];
                outf[(size_t)(bh * L + i) * D + d] = v;
                if (RES_EMIT)
                    outb16[(size_t)(bh * L + i) * DP + d] = f2b(v);
            }
        }
    }
}

// ---------------- launch ----------------
extern "C" void kernel_launch(void* const* d_in, const int* in_sizes, int n_in,
                              void* d_out, int out_size, void* d_ws, size_t ws_size,
                              hipStream_t stream) {
    const int*   q1       = (const int*)  d_in[0];
    const int*   q2       = (const int*)  d_in[1];
    const int*   q1_len   = (const int*)  d_in[2];
    const int*   q2_len   = (const int*)  d_in[3];
    const int*   q1c      = (const int*)  d_in[4];
    const int*   q2c      = (const int*)  d_in[5];
    const float* word_emb = (const float*)d_in[6];
    const float* char_emb = (const float*)d_in[7];
    const float* w3       = (const float*)d_in[8];
    const float* b3       = (const float*)d_in[9];
    const float* w4       = (const float*)d_in[10];
    const float* b4       = (const float*)d_in[11];
    const float* w5       = (const float*)d_in[12];
    const float* b5       = (const float*)d_in[13];
    const float* hw_w     = (const float*)d_in[14];
    const float* hw_b     = (const float*)d_in[15];
    const float* attn_w   = (const float*)d_in[16];
    const float* attn_b   = (const float*)d_in[17];
    float* out = (float*)d_out;

    float*    buf0    = (float*)d_ws;                          // 2*NT*D f32
    float*    buf1    = buf0 + (size_t)2 * NT * D;             // 2*NT*D f32
    float*    bias160 = buf1 + (size_t)2 * NT * D;             // 160 f32
    ushort_t* xb16a   = (ushort_t*)(bias160 + 160);            // 2*NT*DP bf16
    ushort_t* xb16b   = xb16a + (size_t)2 * NT * DP;           // 2*NT*DP bf16
    ushort_t* Wb16    = xb16b + (size_t)2 * NT * DP;           // 512*DP bf16
    ushort_t* Wpad    = Wb16 + (size_t)512 * DP;               // 160*320 bf16
    ushort_t* ceb16   = Wpad + (size_t)160 * 320;              // 100*64 bf16

    // 1. prep + embeddings + conv -> buf0 f32 + xb16a
    conv_prep_kernel<<<226, 256, 0, stream>>>(w3, b3, w4, b4, w5, b5, char_emb,
                                              Wpad, bias160, ceb16);
    wconv_kernel<<<(512 * DP + 255) / 256, 256, 0, stream>>>(hw_w, Wb16);
    wordcopy_kernel<<<2 * NT / 4, 256, 0, stream>>>(q1, q2, word_emb, buf0, xb16a);
    conv_mfma_kernel<<<256, 256, 0, stream>>>(q1c, q2c, ceb16, Wpad, bias160, buf0, xb16a);

    // 2. highway x2 via MFMA (ping-pong f32 + bf16 mirrors)
    dim3 hgrid(8, (2 * NT) / 64);
    highway_mfma_kernel<<<hgrid, 256, 0, stream>>>(xb16a, buf0, Wb16, hw_b, buf1, xb16b);
    highway_mfma_kernel<<<hgrid, 256, 0, stream>>>(xb16b, buf1, Wb16, hw_b, buf0, xb16a);

    // 3. attn layer 0: x = buf0/xb16a -> x1 = buf1/xb16b (residual fused)
    attn_fused_kernel<true><<<NBH, 256, 0, stream>>>(
        buf0, xb16a, q1_len, q2_len, attn_w, attn_b, 0, buf1, xb16b);
    // 4. attn layer 1: x1 -> att -> d_out (f32 only)
    attn_fused_kernel<false><<<NBH, 256, 0, stream>>>(
        buf1, xb16b, q1_len, q2_len, attn_w, attn_b, 1, out, nullptr);
}